// Round 11
// baseline (365.569 us; speedup 1.0000x reference)
//
#include <hip/hip_runtime.h>

#define B_ 4
#define N_ 2048
#define R_ (B_ * N_)      // 8192 rows
#define HID_ 256
#define EMB_ 64
#define IN_DIM_ 70
#define H_ 4
#define HEAD_ 64
#define FFN_ 512
#define LAYERS_ 4

typedef __attribute__((ext_vector_type(8))) short short8;
typedef __attribute__((ext_vector_type(4))) float f32x4;
typedef unsigned short ushort;

static __device__ __forceinline__ ushort f2bf(float f) {
    unsigned u = __builtin_bit_cast(unsigned, f);
    u += 0x7fffu + ((u >> 16) & 1u);   // RNE
    return (ushort)(u >> 16);
}
static __device__ __forceinline__ float bf2f(ushort u) {
    unsigned x = ((unsigned)u) << 16;
    return __builtin_bit_cast(float, x);
}

#define GLOAD_LDS16(g, l)                                              \
    __builtin_amdgcn_global_load_lds(                                  \
        (const __attribute__((address_space(1))) void*)(g),            \
        (__attribute__((address_space(3))) void*)(l), 16, 0, 0)

#define MFMA16(a, b, c) __builtin_amdgcn_mfma_f32_16x16x32_bf16(a, b, c, 0, 0, 0)

// ---------------------------------------------------------------------------
// Pack all weights to bf16, transposed [c][k] layout, in one kernel.
// ---------------------------------------------------------------------------
__global__ __launch_bounds__(256) void pack_weights(const float* __restrict__ valW,
                                                    const float* __restrict__ attnW,
                                                    const float* __restrict__ ffnW1,
                                                    const float* __restrict__ ffnW2,
                                                    const float* __restrict__ outW1,
                                                    ushort* __restrict__ wp) {
    int idx = blockIdx.x * 256 + threadIdx.x;
    float v;
    if (idx < 262144) {
        int l = idx >> 16, c = (idx >> 8) & 255, k = idx & 255;
        v = valW[((l * 4 + (c >> 6)) * 256 + k) * 64 + (c & 63)];
    } else if (idx < 524288) {
        int i2 = idx - 262144;
        int l = i2 >> 16, c = (i2 >> 8) & 255, k = i2 & 255;
        v = attnW[l * 65536 + k * 256 + c];
    } else if (idx < 1048576) {
        int i2 = idx - 524288;
        int l = i2 >> 17, c = (i2 >> 8) & 511, k = i2 & 255;
        v = ffnW1[l * 131072 + k * 512 + c];
    } else if (idx < 1572864) {
        int i2 = idx - 1048576;
        int l = i2 >> 17, c = (i2 >> 9) & 255, k = i2 & 511;
        v = ffnW2[l * 131072 + k * 256 + c];
    } else {
        int i2 = idx - 1572864;
        int c = i2 >> 8, k = i2 & 255;
        v = outW1[k * 256 + c];
    }
    wp[idx] = f2bf(v);
}

// ---------------------------------------------------------------------------
// Input MLP: feats = relu(concat @ in_W + in_b); dual write fp32 + bf16
// ---------------------------------------------------------------------------
__global__ __launch_bounds__(256) void input_mlp(const float* __restrict__ xc,
                                                 const float* __restrict__ emb,
                                                 const float* __restrict__ lat,
                                                 const float* __restrict__ W,
                                                 const float* __restrict__ b,
                                                 float* __restrict__ feats,
                                                 ushort* __restrict__ featsb) {
    __shared__ float xr[8][IN_DIM_ + 2];
    int t = threadIdx.x;
    int row0 = blockIdx.x * 8;
    for (int idx = t; idx < 8 * IN_DIM_; idx += 256) {
        int r = idx / IN_DIM_, f = idx % IN_DIM_;
        int rr = row0 + r;
        float v;
        if (f < 3)       v = xc[rr * 3 + f];
        else if (f < 67) v = emb[rr * EMB_ + (f - 3)];
        else             v = lat[rr * 3 + (f - 67)];
        xr[r][f] = v;
    }
    __syncthreads();
    float acc[8] = {0.f, 0.f, 0.f, 0.f, 0.f, 0.f, 0.f, 0.f};
    for (int f = 0; f < IN_DIM_; ++f) {
        float w = W[f * HID_ + t];
#pragma unroll
        for (int r = 0; r < 8; ++r) acc[r] += xr[r][f] * w;
    }
    float bb = b[t];
#pragma unroll
    for (int r = 0; r < 8; ++r) {
        float v = fmaxf(acc[r] + bb, 0.f);
        feats[(row0 + r) * HID_ + t] = v;
        featsb[(row0 + r) * HID_ + t] = f2bf(v);
    }
}

// ---------------------------------------------------------------------------
// ebuild: E[h][b][i][j] bf16, built once (unchanged from R10).
// ---------------------------------------------------------------------------
__global__ __launch_bounds__(256) void ebuild(const float* __restrict__ xc,
                                              ushort* __restrict__ E) {
    __shared__ float4 civ[64];
    __shared__ float4 cjv[512];
    int t = threadIdx.x;
    int jb = blockIdx.x;
    int ibl = blockIdx.y;
    int b = blockIdx.z;
    const float* xb = xc + (size_t)b * N_ * 3;
    if (t < 64) {
        const float* p = &xb[(ibl * 64 + t) * 3];
        float x = p[0], y = p[1], z = p[2];
        civ[t] = make_float4(x, y, z, x * x + y * y + z * z);
    }
#pragma unroll
    for (int s = 0; s < 2; ++s) {
        int j = s * 256 + t;
        const float* p = &xb[(jb * 512 + j) * 3];
        float x = p[0], y = p[1], z = p[2];
        cjv[j] = make_float4(x, y, z, x * x + y * y + z * z);
    }
    __syncthreads();
    int lane = t & 63, ig = t >> 6;
    float4 cj[8];
#pragma unroll
    for (int e = 0; e < 8; ++e) cj[e] = cjv[lane * 8 + e];
    const float ch0 = -4.f * 1.44269504088896f;
    ushort* Ebase = E + ((size_t)b * 2048 + ibl * 64) * 2048 + (size_t)jb * 512 + lane * 8;

    for (int r = 0; r < 16; ++r) {
        int i = ig * 16 + r;
        float4 ci = civ[i];
        float d[8];
#pragma unroll
        for (int e = 0; e < 8; ++e)
            d[e] = (ci.w + cj[e].w) -
                   2.f * (ci.x * cj[e].x + ci.y * cj[e].y + ci.z * cj[e].z);
        float ch = ch0;
#pragma unroll
        for (int h = 0; h < 4; ++h) {
            float ex[8];
#pragma unroll
            for (int e = 0; e < 8; ++e) ex[e] = exp2f(d[e] * ch);
            union { unsigned u[4]; uint4 v; } pk;
#pragma unroll
            for (int q = 0; q < 4; ++q)
                asm("v_cvt_pk_bf16_f32 %0, %1, %2"
                    : "=v"(pk.u[q]) : "v"(ex[2 * q]), "v"(ex[2 * q + 1]));
            *(uint4*)(Ebase + (size_t)h * 4 * 2048 * 2048 + (size_t)i * 2048) = pk.v;
            ch *= 0.25f;
        }
    }
}

// ---------------------------------------------------------------------------
// pv_gemm v2: E (A-operand) direct global->reg with 1-chunk prefetch
// (per chunk a wave's 16 rows x 128B are full-line reads from L3-resident
// E); V stays LDS-staged (4-wave reuse), dbuf, 1 barrier/chunk.
// ---------------------------------------------------------------------------
__global__ __launch_bounds__(256, 2) void pv_gemm(const ushort* __restrict__ E,
                                                  const ushort* __restrict__ Vt,
                                                  ushort* __restrict__ attb) {
    __shared__ __align__(16) char lds[16384];   // V dbuf 2x8KB
    int t = threadIdx.x;
    int l = t & 63, w = t >> 6;
    int lr = l & 15, g = l >> 4;

    int f = blockIdx.x;
    int xcd = f & 7, s = f >> 3;
    int combo = xcd * 2 + (s >> 5);     // 0..15
    int ib = s & 31;
    int b = combo & 3, h = combo >> 2;
    int i_base = ib * 64;
    int hc = h * 64;

    const ushort* Eb = E + (size_t)(h * 4 + b) * 2048 * 2048;
    int slot = t & 7, trow = t >> 3;

    const ushort* srcB[2];
#pragma unroll
    for (int q = 0; q < 2; ++q) {
        int cl = q * 32 + trow;
        srcB[q] = Vt + (size_t)(b * 256 + hc + cl) * 2048 + ((slot ^ (cl & 7)) << 3);
    }
    auto STAGE = [&](int buf) {
#pragma unroll
        for (int q = 0; q < 2; ++q)
            GLOAD_LDS16(srcB[q], lds + buf * 8192 + q * 4096 + t * 16);
#pragma unroll
        for (int q = 0; q < 2; ++q) srcB[q] += 64;
    };

    f32x4 acc[4] = {};
    f32x4 accd = {};
    short8 ones = {0x3F80, 0x3F80, 0x3F80, 0x3F80, 0x3F80, 0x3F80, 0x3F80, 0x3F80};

    const ushort* ea = Eb + (size_t)(i_base + w * 16 + lr) * 2048 + g * 8;
    STAGE(0);
    short8 a0 = *(const short8*)(ea);
    short8 a1 = *(const short8*)(ea + 32);

    for (int c = 0; c < 32; ++c) {
        __syncthreads();
        if (c + 1 < 32) STAGE((c + 1) & 1);
        short8 na0 = a0, na1 = a1;
        if (c + 1 < 32) {
            na0 = *(const short8*)(ea + (c + 1) * 64);
            na1 = *(const short8*)(ea + (c + 1) * 64 + 32);
        }
        const char* Bs = lds + (c & 1) * 8192;

        accd = MFMA16(a0, ones, accd);
        accd = MFMA16(a1, ones, accd);
#pragma unroll
        for (int n = 0; n < 4; ++n) {
            int cc = n * 16 + lr;
            const char* cb = Bs + cc * 128;
            int sw = (cc & 7) << 4;
            short8 b0 = *(const short8*)(cb + ((g * 16) ^ sw));
            short8 b1 = *(const short8*)(cb + ((64 + g * 16) ^ sw));
            acc[n] = MFMA16(a0, b0, acc[n]);
            acc[n] = MFMA16(a1, b1, acc[n]);
        }
        a0 = na0; a1 = na1;
    }

#pragma unroll
    for (int r = 0; r < 4; ++r) {
        float invd = 1.f / (accd[r] + 1e-8f);
        int row = i_base + w * 16 + g * 4 + r;
        size_t rb = ((size_t)b * N_ + row) * 256 + hc + lr;
#pragma unroll
        for (int n = 0; n < 4; ++n)
            attb[rb + n * 16] = f2bf(acc[n][r] * invd);
    }
}

// ---------------------------------------------------------------------------
// gemmM v2 (KD=256): A staged once to LDS (8KB swizzled), B direct->reg.
// MODE 3: +bias -> transposed bf16 Vt (V-proj layer 0)
// MODE 4: +bias, relu, @W2+b2 -> fp32 d_out (final)
// ---------------------------------------------------------------------------
template <int MODE>
__global__ __launch_bounds__(256) void gemmM(const ushort* __restrict__ A,
                                             const ushort* __restrict__ Bt,
                                             const float* __restrict__ bias,
                                             const float* __restrict__ resid,
                                             const float* __restrict__ lng,
                                             ushort* __restrict__ outb,
                                             float* __restrict__ outf) {
    __shared__ __align__(16) char lds[24576];   // Asp 8K | Ts at +8192
    char* Asp = lds;
    int t = threadIdx.x;
    int l = t & 63, w = t >> 6;
    int lr = l & 15, g = l >> 4;
    int row0 = blockIdx.x * 16;
    int sw_a = (lr & 7) << 4;
    f32x4 acc[4] = {};

#pragma unroll
    for (int shot = 0; shot < 2; ++shot) {
        int si = shot * 256 + t;
        int row = si >> 5, sl = si & 31;
        GLOAD_LDS16(A + (size_t)(row0 + row) * 256 + ((sl ^ (row & 7)) << 3),
                    Asp + si * 16);
    }
    __syncthreads();

#pragma unroll
    for (int c = 0; c < 4; ++c) {
        short8 a0 = *(const short8*)(Asp + lr * 512 + ((c * 128 + g * 16) ^ sw_a));
        short8 a1 = *(const short8*)(Asp + lr * 512 + ((c * 128 + 64 + g * 16) ^ sw_a));
#pragma unroll
        for (int n = 0; n < 4; ++n) {
            int cc = w * 64 + n * 16 + lr;
            const ushort* wb = Bt + (size_t)cc * 256 + c * 64 + g * 8;
            short8 b0 = *(const short8*)(wb);
            short8 b1 = *(const short8*)(wb + 32);
            acc[n] = MFMA16(a0, b0, acc[n]);
            acc[n] = MFMA16(a1, b1, acc[n]);
        }
    }
    __syncthreads();

    if constexpr (MODE == 3) {
        ushort(*Ts)[24] = (ushort(*)[24])(lds + 8192);
#pragma unroll
        for (int n = 0; n < 4; ++n) {
            int c = w * 64 + n * 16 + lr;
            float bi = bias[c];
#pragma unroll
            for (int r = 0; r < 4; ++r)
                Ts[c][g * 4 + r] = f2bf(acc[n][r] + bi);
        }
        __syncthreads();
        {
            int c = t;
            int b = row0 >> 11;
            int n0 = row0 & 2047;
            ushort* dst = outb + ((size_t)(b * 256 + c)) * 2048 + n0;
            *(uint4*)dst = *(uint4*)&Ts[c][0];
            *(uint4*)(dst + 8) = *(uint4*)&Ts[c][8];
        }
    } else {  // MODE 4
        const float* W2 = resid;    // [256][3]
        const float* b2 = lng;      // [3]
        ushort(*Ts)[264] = (ushort(*)[264])(lds + 8192);
#pragma unroll
        for (int n = 0; n < 4; ++n) {
            int c = w * 64 + n * 16 + lr;
            float bi = bias[c];
#pragma unroll
            for (int r = 0; r < 4; ++r)
                Ts[g * 4 + r][c] = f2bf(fmaxf(acc[n][r] + bi, 0.f));
        }
        __syncthreads();
        int row = t >> 4, sg = t & 15;
        float p0 = 0.f, p1 = 0.f, p2 = 0.f;
#pragma unroll
        for (int e = 0; e < 16; ++e) {
            float x = bf2f(Ts[row][sg * 16 + e]);
            const float* wr = &W2[(sg * 16 + e) * 3];
            p0 += x * wr[0];
            p1 += x * wr[1];
            p2 += x * wr[2];
        }
#pragma unroll
        for (int off = 1; off < 16; off <<= 1) {
            p0 += __shfl_xor(p0, off, 64);
            p1 += __shfl_xor(p1, off, 64);
            p2 += __shfl_xor(p2, off, 64);
        }
        if (sg == 0) {
            int gr = row0 + row;
            outf[gr * 3 + 0] = p0 + b2[0];
            outf[gr * 3 + 1] = p1 + b2[1];
            outf[gr * 3 + 2] = p2 + b2[2];
        }
    }
}

// ---------------------------------------------------------------------------
// gemm_layer v2: attn-proj -> LN1 -> FFN1 -> ReLU -> FFN2 -> LN2 -> V(l+1).
// Weights are NEVER staged (zero cross-wave reuse): direct global->VGPR,
// full-128B-line reads from L2. A-operands in LDS (attb once; x1/x2 in Asp;
// hid). 7 barriers total. LDS 26KB.
// ---------------------------------------------------------------------------
__global__ __launch_bounds__(256) void gemm_layer(
        const ushort* __restrict__ attb,
        const ushort* __restrict__ Wat, const float* __restrict__ pb,
        float* __restrict__ feats,
        const float* __restrict__ ln1g, const float* __restrict__ ln1b,
        const ushort* __restrict__ W1t, const float* __restrict__ b1,
        const ushort* __restrict__ W2t, const float* __restrict__ b2,
        const float* __restrict__ ln2g, const float* __restrict__ ln2b,
        ushort* __restrict__ featsb,
        const ushort* __restrict__ WvN, const float* __restrict__ vbN,
        ushort* __restrict__ Vt) {
    __shared__ __align__(16) char lds[26624];
    char* Asp = lds;                         // 8KB: attb -> x1 -> x2
    char* hidp = lds + 8192;                 // 16KB; Ts overlay in P3
    float* red1 = (float*)(lds + 24576);     // [16][4]
    float* red2 = (float*)(lds + 25088);

    int t = threadIdx.x;
    int l = t & 63, w = t >> 6;
    int lr = l & 15, g = l >> 4;
    int row0 = blockIdx.x * 16;
    int sw_a = (lr & 7) << 4;

    // ---- stage attb A once (8KB) ----
#pragma unroll
    for (int shot = 0; shot < 2; ++shot) {
        int si = shot * 256 + t;
        int row = si >> 5, sl = si & 31;
        GLOAD_LDS16(attb + (size_t)(row0 + row) * 256 + ((sl ^ (row & 7)) << 3),
                    Asp + si * 16);
    }
    __syncthreads();                                           // (1)

    // ---- P0: attn-proj (KD=256), B = Wat direct ----
    f32x4 acc[4] = {};
#pragma unroll
    for (int c = 0; c < 4; ++c) {
        short8 a0 = *(const short8*)(Asp + lr * 512 + ((c * 128 + g * 16) ^ sw_a));
        short8 a1 = *(const short8*)(Asp + lr * 512 + ((c * 128 + 64 + g * 16) ^ sw_a));
#pragma unroll
        for (int n = 0; n < 4; ++n) {
            int cc = w * 64 + n * 16 + lr;
            const ushort* wb = Wat + (size_t)cc * 256 + c * 64 + g * 8;
            short8 b0 = *(const short8*)(wb);
            short8 b1 = *(const short8*)(wb + 32);
            acc[n] = MFMA16(a0, b0, acc[n]);
            acc[n] = MFMA16(a1, b1, acc[n]);
        }
    }

    // ---- LN1 (x1 in regs; bf16 -> Asp) ----
    float x1v[4][4];
    {
        float s1[4] = {0.f, 0.f, 0.f, 0.f}, s2[4] = {0.f, 0.f, 0.f, 0.f};
#pragma unroll
        for (int n = 0; n < 4; ++n) {
            int c = w * 64 + n * 16 + lr;
            float bi = pb[c];
#pragma unroll
            for (int r = 0; r < 4; ++r) {
                int row = row0 + g * 4 + r;
                float v = acc[n][r] + bi + feats[(size_t)row * 256 + c];
                x1v[n][r] = v;
                s1[r] += v;
                s2[r] += v * v;
            }
        }
#pragma unroll
        for (int off = 1; off < 16; off <<= 1) {
#pragma unroll
            for (int r = 0; r < 4; ++r) {
                s1[r] += __shfl_xor(s1[r], off, 64);
                s2[r] += __shfl_xor(s2[r], off, 64);
            }
        }
        if (lr == 0) {
#pragma unroll
            for (int r = 0; r < 4; ++r) {
                red1[(g * 4 + r) * 4 + w] = s1[r];
                red2[(g * 4 + r) * 4 + w] = s2[r];
            }
        }
        __syncthreads();                                       // (2)
#pragma unroll
        for (int n = 0; n < 4; ++n) {
            int c = w * 64 + n * 16 + lr;
            float gg = ln1g[c], bb = ln1b[c];
#pragma unroll
            for (int r = 0; r < 4; ++r) {
                int rr = g * 4 + r;
                float m1 = red1[rr * 4] + red1[rr * 4 + 1] + red1[rr * 4 + 2] + red1[rr * 4 + 3];
                float m2 = red2[rr * 4] + red2[rr * 4 + 1] + red2[rr * 4 + 2] + red2[rr * 4 + 3];
                float mu = m1 * (1.f / 256.f);
                float var = m2 * (1.f / 256.f) - mu * mu;
                float rstd = rsqrtf(var + 1e-5f);
                float o = (x1v[n][r] - mu) * rstd * gg + bb;
                x1v[n][r] = o;
                *(ushort*)(Asp + rr * 512 + ((2 * c) ^ ((rr & 7) << 4))) = f2bf(o);
            }
        }
    }
    __syncthreads();                                           // (3)

    // ---- P1: FFN1 (KD=256, 512 cols in 2 halves), relu -> hid LDS ----
#pragma unroll
    for (int ch = 0; ch < 2; ++ch) {
        f32x4 acc1[4] = {};
#pragma unroll
        for (int c = 0; c < 4; ++c) {
            short8 a0 = *(const short8*)(Asp + lr * 512 + ((c * 128 + g * 16) ^ sw_a));
            short8 a1 = *(const short8*)(Asp + lr * 512 + ((c * 128 + 64 + g * 16) ^ sw_a));
#pragma unroll
            for (int n = 0; n < 4; ++n) {
                int cf = ch * 256 + w * 64 + n * 16 + lr;
                const ushort* wb = W1t + (size_t)cf * 256 + c * 64 + g * 8;
                short8 b0 = *(const short8*)(wb);
                short8 b1 = *(const short8*)(wb + 32);
                acc1[n] = MFMA16(a0, b0, acc1[n]);
                acc1[n] = MFMA16(a1, b1, acc1[n]);
            }
        }
#pragma unroll
        for (int n = 0; n < 4; ++n) {
            int cf = ch * 256 + w * 64 + n * 16 + lr;
            float bi = b1[cf];
#pragma unroll
            for (int r = 0; r < 4; ++r) {
                int rw = g * 4 + r;
                float v = fmaxf(acc1[n][r] + bi, 0.f);
                int byte = rw * 1024 + ((cf * 2) ^ ((rw & 7) << 4));
                *(ushort*)(hidp + byte) = f2bf(v);
            }
        }
    }
    __syncthreads();                                           // (4)

    // ---- P2: FFN2 (KD=512), A = hid ----
    f32x4 acc2[4] = {};
#pragma unroll
    for (int c = 0; c < 8; ++c) {
        short8 a0 = *(const short8*)(hidp + lr * 1024 + ((c * 128 + g * 16) ^ sw_a));
        short8 a1 = *(const short8*)(hidp + lr * 1024 + ((c * 128 + 64 + g * 16) ^ sw_a));
#pragma unroll
        for (int n = 0; n < 4; ++n) {
            int cc = w * 64 + n * 16 + lr;
            const ushort* wb = W2t + (size_t)cc * 512 + c * 64 + g * 8;
            short8 b0 = *(const short8*)(wb);
            short8 b1 = *(const short8*)(wb + 32);
            acc2[n] = MFMA16(a0, b0, acc2[n]);
            acc2[n] = MFMA16(a1, b1, acc2[n]);
        }
    }

    // ---- LN2 (resid = x1 regs) -> feats fp32+bf16; x2 -> Asp ----
#pragma unroll
    for (int n = 0; n < 4; ++n) {
        int c = w * 64 + n * 16 + lr;
        float bi = b2[c];
#pragma unroll
        for (int r = 0; r < 4; ++r)
            acc2[n][r] = acc2[n][r] + bi + x1v[n][r];
    }
    {
        float s1[4] = {0.f, 0.f, 0.f, 0.f}, s2[4] = {0.f, 0.f, 0.f, 0.f};
#pragma unroll
        for (int n = 0; n < 4; ++n)
#pragma unroll
            for (int r = 0; r < 4; ++r) {
                s1[r] += acc2[n][r];
                s2[r] += acc2[n][r] * acc2[n][r];
            }
#pragma unroll
        for (int off = 1; off < 16; off <<= 1) {
#pragma unroll
            for (int r = 0; r < 4; ++r) {
                s1[r] += __shfl_xor(s1[r], off, 64);
                s2[r] += __shfl_xor(s2[r], off, 64);
            }
        }
        if (lr == 0) {
#pragma unroll
            for (int r = 0; r < 4; ++r) {
                red1[(g * 4 + r) * 4 + w] = s1[r];
                red2[(g * 4 + r) * 4 + w] = s2[r];
            }
        }
        __syncthreads();                                       // (5)
#pragma unroll
        for (int n = 0; n < 4; ++n) {
            int c = w * 64 + n * 16 + lr;
            float gg = ln2g[c], bb = ln2b[c];
#pragma unroll
            for (int r = 0; r < 4; ++r) {
                int rr = g * 4 + r;
                float m1 = red1[rr * 4] + red1[rr * 4 + 1] + red1[rr * 4 + 2] + red1[rr * 4 + 3];
                float m2 = red2[rr * 4] + red2[rr * 4 + 1] + red2[rr * 4 + 2] + red2[rr * 4 + 3];
                float mu = m1 * (1.f / 256.f);
                float var = m2 * (1.f / 256.f) - mu * mu;
                float rstd = rsqrtf(var + 1e-5f);
                int row = row0 + rr;
                float o = (acc2[n][r] - mu) * rstd * gg + bb;
                feats[(size_t)row * 256 + c] = o;
                ushort ob = f2bf(o);
                featsb[(size_t)row * 256 + c] = ob;
                *(ushort*)(Asp + rr * 512 + ((2 * c) ^ ((rr & 7) << 4))) = ob;
            }
        }
    }
    __syncthreads();                                           // (6)

    // ---- P3: V(l+1) = x2 @ WvN (KD=256), transposed bf16 -> Vt ----
    if (WvN) {
        f32x4 acc3[4] = {};
#pragma unroll
        for (int c = 0; c < 4; ++c) {
            short8 a0 = *(const short8*)(Asp + lr * 512 + ((c * 128 + g * 16) ^ sw_a));
            short8 a1 = *(const short8*)(Asp + lr * 512 + ((c * 128 + 64 + g * 16) ^ sw_a));
#pragma unroll
            for (int n = 0; n < 4; ++n) {
                int cc = w * 64 + n * 16 + lr;
                const ushort* wb = WvN + (size_t)cc * 256 + c * 64 + g * 8;
                short8 b0 = *(const short8*)(wb);
                short8 b1 = *(const short8*)(wb + 32);
                acc3[n] = MFMA16(a0, b0, acc3[n]);
                acc3[n] = MFMA16(a1, b1, acc3[n]);
            }
        }
        ushort(*Ts)[24] = (ushort(*)[24])hidp;   // 12KB <= 16KB
#pragma unroll
        for (int n = 0; n < 4; ++n) {
            int c = w * 64 + n * 16 + lr;
            float bi = vbN[c];
#pragma unroll
            for (int r = 0; r < 4; ++r)
                Ts[c][g * 4 + r] = f2bf(acc3[n][r] + bi);
        }
        __syncthreads();                                       // (7)
        {
            int c = t;
            int b = row0 >> 11;
            int n0 = row0 & 2047;
            ushort* dst = Vt + ((size_t)(b * 256 + c)) * 2048 + n0;
            *(uint4*)dst = *(uint4*)&Ts[c][0];
            *(uint4*)(dst + 8) = *(uint4*)&Ts[c][8];
        }
    }
}

// ---------------------------------------------------------------------------
extern "C" void kernel_launch(void* const* d_in, const int* in_sizes, int n_in,
                              void* d_out, int out_size, void* d_ws, size_t ws_size,
                              hipStream_t stream) {
    const float* lat    = (const float*)d_in[0];
    const float* xc     = (const float*)d_in[1];
    const float* emb    = (const float*)d_in[2];
    const float* in_W   = (const float*)d_in[3];
    const float* in_b   = (const float*)d_in[4];
    const float* val_W  = (const float*)d_in[5];
    const float* val_b  = (const float*)d_in[6];
    const float* attn_W = (const float*)d_in[7];
    const float* attn_b = (const float*)d_in[8];
    const float* ln1_g  = (const float*)d_in[9];
    const float* ln1_b  = (const float*)d_in[10];
    const float* ln2_g  = (const float*)d_in[11];
    const float* ln2_b  = (const float*)d_in[12];
    const float* ffn_W1 = (const float*)d_in[13];
    const float* ffn_b1 = (const float*)d_in[14];
    const float* ffn_W2 = (const float*)d_in[15];
    const float* ffn_b2 = (const float*)d_in[16];
    const float* out_W1 = (const float*)d_in[17];
    const float* out_b1 = (const float*)d_in[18];
    const float* out_W2 = (const float*)d_in[19];
    const float* out_b2 = (const float*)d_in[20];

    char* W = (char*)d_ws;
    float*  feats  = (float*)W;                                // 8 MB
    ushort* featsb = (ushort*)(W + (8u << 20));                // 4 MB
    ushort* attb   = (ushort*)(W + (12u << 20));               // 4 MB
    ushort* Vt     = (ushort*)(W + (16u << 20));               // 4 MB
    ushort* wp     = (ushort*)(W + (20u << 20));               // 3.2 MB
    ushort* E      = (ushort*)(W + (24u << 20));               // 128 MiB
    ushort* Wvt  = wp;
    ushort* Wat  = wp + 262144;
    ushort* W1t  = wp + 524288;
    ushort* W2t  = wp + 1048576;
    ushort* Wo1t = wp + 1572864;

    pack_weights<<<6400, 256, 0, stream>>>(val_W, attn_W, ffn_W1, ffn_W2, out_W1, wp);
    input_mlp<<<R_ / 8, 256, 0, stream>>>(xc, emb, lat, in_W, in_b, feats, featsb);
    ebuild<<<dim3(4, 32, B_), 256, 0, stream>>>(xc, E);

    gemmM<3><<<R_ / 16, 256, 0, stream>>>(
        featsb, Wvt, val_b, nullptr, nullptr, Vt, nullptr);

    for (int l = 0; l < LAYERS_; ++l) {
        pv_gemm<<<512, 256, 0, stream>>>(E, Vt, attb);
        const ushort* WvN = (l + 1 < LAYERS_) ? (Wvt + (l + 1) * 65536) : nullptr;
        const float* vbN = val_b + ((l + 1 < LAYERS_) ? (l + 1) * 256 : 0);
        gemm_layer<<<R_ / 16, 256, 0, stream>>>(
            attb, Wat + l * 65536, attn_b + l * 256,
            feats, ln1_g + l * 256, ln1_b + l * 256,
            W1t + l * 131072, ffn_b1 + l * 512,
            W2t + l * 131072, ffn_b2 + l * 256,
            ln2_g + l * 256, ln2_b + l * 256,
            featsb, WvN, vbN, Vt);
    }

    gemmM<4><<<R_ / 16, 256, 0, stream>>>(
        featsb, Wo1t, out_b1, out_W2, out_b2, nullptr, (float*)d_out);
}

// Round 12
// 310.273 us; speedup vs baseline: 1.1782x; 1.1782x over previous
//
#include <hip/hip_runtime.h>

#define B_ 4
#define N_ 2048
#define R_ (B_ * N_)      // 8192 rows
#define HID_ 256
#define EMB_ 64
#define IN_DIM_ 70
#define H_ 4
#define HEAD_ 64
#define FFN_ 512
#define LAYERS_ 4

typedef __attribute__((ext_vector_type(8))) short short8;
typedef __attribute__((ext_vector_type(4))) float f32x4;
typedef unsigned short ushort;

static __device__ __forceinline__ ushort f2bf(float f) {
    unsigned u = __builtin_bit_cast(unsigned, f);
    u += 0x7fffu + ((u >> 16) & 1u);   // RNE
    return (ushort)(u >> 16);
}
static __device__ __forceinline__ float bf2f(ushort u) {
    unsigned x = ((unsigned)u) << 16;
    return __builtin_bit_cast(float, x);
}

#define GLOAD_LDS16(g, l)                                              \
    __builtin_amdgcn_global_load_lds(                                  \
        (const __attribute__((address_space(1))) void*)(g),            \
        (__attribute__((address_space(3))) void*)(l), 16, 0, 0)

#define MFMA16(a, b, c) __builtin_amdgcn_mfma_f32_16x16x32_bf16(a, b, c, 0, 0, 0)

// ---------------------------------------------------------------------------
// Pack all weights to bf16, transposed [c][k] layout.
// ---------------------------------------------------------------------------
__global__ __launch_bounds__(256) void pack_weights(const float* __restrict__ valW,
                                                    const float* __restrict__ attnW,
                                                    const float* __restrict__ ffnW1,
                                                    const float* __restrict__ ffnW2,
                                                    const float* __restrict__ outW1,
                                                    ushort* __restrict__ wp) {
    int idx = blockIdx.x * 256 + threadIdx.x;
    float v;
    if (idx < 262144) {
        int l = idx >> 16, c = (idx >> 8) & 255, k = idx & 255;
        v = valW[((l * 4 + (c >> 6)) * 256 + k) * 64 + (c & 63)];
    } else if (idx < 524288) {
        int i2 = idx - 262144;
        int l = i2 >> 16, c = (i2 >> 8) & 255, k = i2 & 255;
        v = attnW[l * 65536 + k * 256 + c];
    } else if (idx < 1048576) {
        int i2 = idx - 524288;
        int l = i2 >> 17, c = (i2 >> 8) & 511, k = i2 & 255;
        v = ffnW1[l * 131072 + k * 512 + c];
    } else if (idx < 1572864) {
        int i2 = idx - 1048576;
        int l = i2 >> 17, c = (i2 >> 9) & 255, k = i2 & 511;
        v = ffnW2[l * 131072 + k * 256 + c];
    } else {
        int i2 = idx - 1572864;
        int c = i2 >> 8, k = i2 & 255;
        v = outW1[k * 256 + c];
    }
    wp[idx] = f2bf(v);
}

// ---------------------------------------------------------------------------
// Input MLP
// ---------------------------------------------------------------------------
__global__ __launch_bounds__(256) void input_mlp(const float* __restrict__ xc,
                                                 const float* __restrict__ emb,
                                                 const float* __restrict__ lat,
                                                 const float* __restrict__ W,
                                                 const float* __restrict__ b,
                                                 float* __restrict__ feats,
                                                 ushort* __restrict__ featsb) {
    __shared__ float xr[8][IN_DIM_ + 2];
    int t = threadIdx.x;
    int row0 = blockIdx.x * 8;
    for (int idx = t; idx < 8 * IN_DIM_; idx += 256) {
        int r = idx / IN_DIM_, f = idx % IN_DIM_;
        int rr = row0 + r;
        float v;
        if (f < 3)       v = xc[rr * 3 + f];
        else if (f < 67) v = emb[rr * EMB_ + (f - 3)];
        else             v = lat[rr * 3 + (f - 67)];
        xr[r][f] = v;
    }
    __syncthreads();
    float acc[8] = {0.f, 0.f, 0.f, 0.f, 0.f, 0.f, 0.f, 0.f};
    for (int f = 0; f < IN_DIM_; ++f) {
        float w = W[f * HID_ + t];
#pragma unroll
        for (int r = 0; r < 8; ++r) acc[r] += xr[r][f] * w;
    }
    float bb = b[t];
#pragma unroll
    for (int r = 0; r < 8; ++r) {
        float v = fmaxf(acc[r] + bb, 0.f);
        feats[(row0 + r) * HID_ + t] = v;
        featsb[(row0 + r) * HID_ + t] = f2bf(v);
    }
}

// ---------------------------------------------------------------------------
// ebuild (unchanged)
// ---------------------------------------------------------------------------
__global__ __launch_bounds__(256) void ebuild(const float* __restrict__ xc,
                                              ushort* __restrict__ E) {
    __shared__ float4 civ[64];
    __shared__ float4 cjv[512];
    int t = threadIdx.x;
    int jb = blockIdx.x;
    int ibl = blockIdx.y;
    int b = blockIdx.z;
    const float* xb = xc + (size_t)b * N_ * 3;
    if (t < 64) {
        const float* p = &xb[(ibl * 64 + t) * 3];
        float x = p[0], y = p[1], z = p[2];
        civ[t] = make_float4(x, y, z, x * x + y * y + z * z);
    }
#pragma unroll
    for (int s = 0; s < 2; ++s) {
        int j = s * 256 + t;
        const float* p = &xb[(jb * 512 + j) * 3];
        float x = p[0], y = p[1], z = p[2];
        cjv[j] = make_float4(x, y, z, x * x + y * y + z * z);
    }
    __syncthreads();
    int lane = t & 63, ig = t >> 6;
    float4 cj[8];
#pragma unroll
    for (int e = 0; e < 8; ++e) cj[e] = cjv[lane * 8 + e];
    const float ch0 = -4.f * 1.44269504088896f;
    ushort* Ebase = E + ((size_t)b * 2048 + ibl * 64) * 2048 + (size_t)jb * 512 + lane * 8;

    for (int r = 0; r < 16; ++r) {
        int i = ig * 16 + r;
        float4 ci = civ[i];
        float d[8];
#pragma unroll
        for (int e = 0; e < 8; ++e)
            d[e] = (ci.w + cj[e].w) -
                   2.f * (ci.x * cj[e].x + ci.y * cj[e].y + ci.z * cj[e].z);
        float ch = ch0;
#pragma unroll
        for (int h = 0; h < 4; ++h) {
            float ex[8];
#pragma unroll
            for (int e = 0; e < 8; ++e) ex[e] = exp2f(d[e] * ch);
            union { unsigned u[4]; uint4 v; } pk;
#pragma unroll
            for (int q = 0; q < 4; ++q)
                asm("v_cvt_pk_bf16_f32 %0, %1, %2"
                    : "=v"(pk.u[q]) : "v"(ex[2 * q]), "v"(ex[2 * q + 1]));
            *(uint4*)(Ebase + (size_t)h * 4 * 2048 * 2048 + (size_t)i * 2048) = pk.v;
            ch *= 0.25f;
        }
    }
}

// ---------------------------------------------------------------------------
// pv_gemm (R11 v2, unchanged — E direct->reg prefetched, V LDS dbuf)
// ---------------------------------------------------------------------------
__global__ __launch_bounds__(256, 2) void pv_gemm(const ushort* __restrict__ E,
                                                  const ushort* __restrict__ Vt,
                                                  ushort* __restrict__ attb) {
    __shared__ __align__(16) char lds[16384];
    int t = threadIdx.x;
    int l = t & 63, w = t >> 6;
    int lr = l & 15, g = l >> 4;

    int f = blockIdx.x;
    int xcd = f & 7, s = f >> 3;
    int combo = xcd * 2 + (s >> 5);
    int ib = s & 31;
    int b = combo & 3, h = combo >> 2;
    int i_base = ib * 64;
    int hc = h * 64;

    const ushort* Eb = E + (size_t)(h * 4 + b) * 2048 * 2048;
    int slot = t & 7, trow = t >> 3;

    const ushort* srcB[2];
#pragma unroll
    for (int q = 0; q < 2; ++q) {
        int cl = q * 32 + trow;
        srcB[q] = Vt + (size_t)(b * 256 + hc + cl) * 2048 + ((slot ^ (cl & 7)) << 3);
    }
    auto STAGE = [&](int buf) {
#pragma unroll
        for (int q = 0; q < 2; ++q)
            GLOAD_LDS16(srcB[q], lds + buf * 8192 + q * 4096 + t * 16);
#pragma unroll
        for (int q = 0; q < 2; ++q) srcB[q] += 64;
    };

    f32x4 acc[4] = {};
    f32x4 accd = {};
    short8 ones = {0x3F80, 0x3F80, 0x3F80, 0x3F80, 0x3F80, 0x3F80, 0x3F80, 0x3F80};

    const ushort* ea = Eb + (size_t)(i_base + w * 16 + lr) * 2048 + g * 8;
    STAGE(0);
    short8 a0 = *(const short8*)(ea);
    short8 a1 = *(const short8*)(ea + 32);

    for (int c = 0; c < 32; ++c) {
        __syncthreads();
        if (c + 1 < 32) STAGE((c + 1) & 1);
        short8 na0 = a0, na1 = a1;
        if (c + 1 < 32) {
            na0 = *(const short8*)(ea + (c + 1) * 64);
            na1 = *(const short8*)(ea + (c + 1) * 64 + 32);
        }
        const char* Bs = lds + (c & 1) * 8192;

        accd = MFMA16(a0, ones, accd);
        accd = MFMA16(a1, ones, accd);
#pragma unroll
        for (int n = 0; n < 4; ++n) {
            int cc = n * 16 + lr;
            const char* cb = Bs + cc * 128;
            int sw = (cc & 7) << 4;
            short8 b0 = *(const short8*)(cb + ((g * 16) ^ sw));
            short8 b1 = *(const short8*)(cb + ((64 + g * 16) ^ sw));
            acc[n] = MFMA16(a0, b0, acc[n]);
            acc[n] = MFMA16(a1, b1, acc[n]);
        }
        a0 = na0; a1 = na1;
    }

#pragma unroll
    for (int r = 0; r < 4; ++r) {
        float invd = 1.f / (accd[r] + 1e-8f);
        int row = i_base + w * 16 + g * 4 + r;
        size_t rb = ((size_t)b * N_ + row) * 256 + hc + lr;
#pragma unroll
        for (int n = 0; n < 4; ++n)
            attb[rb + n * 16] = f2bf(acc[n][r] * invd);
    }
}

// ---------------------------------------------------------------------------
// gemmM (R10 revert): LDS-dbuf staged A+B, KD=256. MODE 3 / MODE 4.
// ---------------------------------------------------------------------------
template <int MODE>
__global__ __launch_bounds__(256) void gemmM(const ushort* __restrict__ A,
                                             const ushort* __restrict__ Bt,
                                             const float* __restrict__ bias,
                                             const float* __restrict__ resid,
                                             const float* __restrict__ lng,
                                             ushort* __restrict__ outb,
                                             float* __restrict__ outf) {
    __shared__ __align__(16) char lds[69632];
    int t = threadIdx.x;
    int l = t & 63, w = t >> 6;
    int lr = l & 15, g = l >> 4;
    int row0 = blockIdx.x * 16;
    f32x4 acc[4] = {};

    const ushort* srcA = A + (size_t)(row0 + (t >> 3)) * 256 + (((t & 7) ^ ((t >> 3) & 7)) << 3);
    const ushort* srcB[8];
#pragma unroll
    for (int q = 0; q < 8; ++q) {
        int cl = q * 32 + (t >> 3);
        srcB[q] = Bt + (size_t)cl * 256 + (((t & 7) ^ (cl & 7)) << 3);
    }
    auto STAGE = [&](int buf) {
        if (t < 128) GLOAD_LDS16(srcA, lds + buf * 2048 + t * 16);
#pragma unroll
        for (int q = 0; q < 8; ++q)
            GLOAD_LDS16(srcB[q], lds + 4096 + buf * 32768 + q * 4096 + t * 16);
        srcA += 64;
#pragma unroll
        for (int q = 0; q < 8; ++q) srcB[q] += 64;
    };

    int sw_a = (lr & 7) << 4;
    int aoff = lr * 128;

    STAGE(0);
#pragma unroll
    for (int c = 0; c < 4; ++c) {
        __syncthreads();
        if (c + 1 < 4) STAGE((c + 1) & 1);
        const char* As = lds + (c & 1) * 2048;
        const char* Ws = lds + 4096 + (c & 1) * 32768;

        short8 a0 = *(const short8*)(As + aoff + ((g * 16) ^ sw_a));
        short8 a1 = *(const short8*)(As + aoff + ((64 + g * 16) ^ sw_a));
#pragma unroll
        for (int n = 0; n < 4; ++n) {
            int cc = w * 64 + n * 16 + lr;
            const char* cb = Ws + cc * 128;
            int sw = (cc & 7) << 4;
            short8 b0 = *(const short8*)(cb + ((g * 16) ^ sw));
            short8 b1 = *(const short8*)(cb + ((64 + g * 16) ^ sw));
            acc[n] = MFMA16(a0, b0, acc[n]);
            acc[n] = MFMA16(a1, b1, acc[n]);
        }
    }
    __syncthreads();

    if constexpr (MODE == 3) {
        ushort(*Ts)[24] = (ushort(*)[24])lds;
#pragma unroll
        for (int n = 0; n < 4; ++n) {
            int c = w * 64 + n * 16 + lr;
            float bi = bias[c];
#pragma unroll
            for (int r = 0; r < 4; ++r)
                Ts[c][g * 4 + r] = f2bf(acc[n][r] + bi);
        }
        __syncthreads();
        {
            int c = t;
            int b = row0 >> 11;
            int n0 = row0 & 2047;
            ushort* dst = outb + ((size_t)(b * 256 + c)) * 2048 + n0;
            *(uint4*)dst = *(uint4*)&Ts[c][0];
            *(uint4*)(dst + 8) = *(uint4*)&Ts[c][8];
        }
    } else {  // MODE 4
        const float* W2 = resid;    // [256][3]
        const float* b2 = lng;      // [3]
        ushort(*Ts)[264] = (ushort(*)[264])lds;
#pragma unroll
        for (int n = 0; n < 4; ++n) {
            int c = w * 64 + n * 16 + lr;
            float bi = bias[c];
#pragma unroll
            for (int r = 0; r < 4; ++r)
                Ts[g * 4 + r][c] = f2bf(fmaxf(acc[n][r] + bi, 0.f));
        }
        __syncthreads();
        int row = t >> 4, sg = t & 15;
        float p0 = 0.f, p1 = 0.f, p2 = 0.f;
#pragma unroll
        for (int e = 0; e < 16; ++e) {
            float x = bf2f(Ts[row][sg * 16 + e]);
            const float* wr = &W2[(sg * 16 + e) * 3];
            p0 += x * wr[0];
            p1 += x * wr[1];
            p2 += x * wr[2];
        }
#pragma unroll
        for (int off = 1; off < 16; off <<= 1) {
            p0 += __shfl_xor(p0, off, 64);
            p1 += __shfl_xor(p1, off, 64);
            p2 += __shfl_xor(p2, off, 64);
        }
        if (sg == 0) {
            int gr = row0 + row;
            outf[gr * 3 + 0] = p0 + b2[0];
            outf[gr * 3 + 1] = p1 + b2[1];
            outf[gr * 3 + 2] = p2 + b2[2];
        }
    }
}

// ---------------------------------------------------------------------------
// gemm_layer v3: single-barrier dbuf weight pipeline, K-chunk=32.
// Wsp layout: buf*16K + slot*4K + ((col*16) ^ ((slot&1)<<8))  [2-way free].
// Per chunk: bar; compute(c) from Wsp[c&1]; WSTORE(c+1); WLOAD(c+2).
// Loads always issued >= 1 full chunk before their ds_write waits on them;
// next phase's chunk-0 loads fly during LN epilogues. LDS 58.4KB.
// ---------------------------------------------------------------------------
__global__ __launch_bounds__(256) void gemm_layer(
        const ushort* __restrict__ attb,
        const ushort* __restrict__ Wat, const float* __restrict__ pb,
        float* __restrict__ feats,
        const float* __restrict__ ln1g, const float* __restrict__ ln1b,
        const ushort* __restrict__ W1t, const float* __restrict__ b1,
        const ushort* __restrict__ W2t, const float* __restrict__ b2,
        const float* __restrict__ ln2g, const float* __restrict__ ln2b,
        ushort* __restrict__ featsb,
        const ushort* __restrict__ WvN, const float* __restrict__ vbN,
        ushort* __restrict__ Vt) {
    __shared__ __align__(16) char lds[58368];
    char* Asp  = lds;                        // 8KB: attb -> x1 -> x2
    char* hidp = lds + 8192;                 // 16KB; Ts overlay in P3
    char* Wsp  = lds + 24576;                // 2 x 16KB
    float* red1 = (float*)(lds + 57344);     // [16][4]
    float* red2 = (float*)(lds + 57856);

    int t = threadIdx.x;
    int l = t & 63, w = t >> 6;
    int lr = l & 15, g = l >> 4;
    int row0 = blockIdx.x * 16;
    int sw_a = (lr & 7) << 4;
    int slot4 = t & 3;          // k-slot (8 bf16)
    int col4 = t >> 2;          // 0..63

    uint4 wr0, wr1, wr2, wr3;
    auto WLOAD = [&](const ushort* Wb, int stride, int colbase, int kb) {
#pragma unroll
        for (int q = 0; q < 4; ++q) {
            int cl = colbase + q * 64 + col4;
            uint4 v = *(const uint4*)(Wb + (size_t)cl * stride + kb + slot4 * 8);
            if (q == 0) wr0 = v; else if (q == 1) wr1 = v;
            else if (q == 2) wr2 = v; else wr3 = v;
        }
    };
    int wxor = (slot4 & 1) << 8;
    auto WSTORE = [&](int buf) {
        char* base = Wsp + buf * 16384 + slot4 * 4096;
        *(uint4*)(base + (((0 * 64 + col4) * 16) ^ wxor)) = wr0;
        *(uint4*)(base + (((1 * 64 + col4) * 16) ^ wxor)) = wr1;
        *(uint4*)(base + (((2 * 64 + col4) * 16) ^ wxor)) = wr2;
        *(uint4*)(base + (((3 * 64 + col4) * 16) ^ wxor)) = wr3;
    };
    auto BFRAG = [&](int buf, int cc) -> short8 {
        return *(const short8*)(Wsp + buf * 16384 + g * 4096 +
                                ((cc * 16) ^ ((g & 1) << 8)));
    };

    // ---- prologue: stage attb A; pipeline W chunk 0/1 ----
#pragma unroll
    for (int shot = 0; shot < 2; ++shot) {
        int si = shot * 256 + t;
        int row = si >> 5, sl = si & 31;
        GLOAD_LDS16(attb + (size_t)(row0 + row) * 256 + ((sl ^ (row & 7)) << 3),
                    Asp + si * 16);
    }
    WLOAD(Wat, 256, 0, 0);
    WSTORE(0);
    WLOAD(Wat, 256, 0, 32);

    // ---- P0: attn-proj, 8 chunks ----
    f32x4 acc0[4] = {};
#pragma unroll
    for (int c = 0; c < 8; ++c) {
        __syncthreads();
        short8 a = *(const short8*)(Asp + lr * 512 + ((c * 64 + g * 16) ^ sw_a));
#pragma unroll
        for (int n = 0; n < 4; ++n)
            acc0[n] = MFMA16(a, BFRAG(c & 1, w * 64 + n * 16 + lr), acc0[n]);
        if (c < 6)       { WSTORE((c + 1) & 1); WLOAD(Wat, 256, 0, (c + 2) * 32); }
        else if (c == 6) { WSTORE(1);           WLOAD(W1t, 256, 0, 0); }
    }

    // ---- LN1 (x1 in regs; bf16 -> Asp) ----
    float x1v[4][4];
    {
        float s1[4] = {0.f, 0.f, 0.f, 0.f}, s2[4] = {0.f, 0.f, 0.f, 0.f};
#pragma unroll
        for (int n = 0; n < 4; ++n) {
            int c = w * 64 + n * 16 + lr;
            float bi = pb[c];
#pragma unroll
            for (int r = 0; r < 4; ++r) {
                int row = row0 + g * 4 + r;
                float v = acc0[n][r] + bi + feats[(size_t)row * 256 + c];
                x1v[n][r] = v;
                s1[r] += v;
                s2[r] += v * v;
            }
        }
#pragma unroll
        for (int off = 1; off < 16; off <<= 1) {
#pragma unroll
            for (int r = 0; r < 4; ++r) {
                s1[r] += __shfl_xor(s1[r], off, 64);
                s2[r] += __shfl_xor(s2[r], off, 64);
            }
        }
        if (lr == 0) {
#pragma unroll
            for (int r = 0; r < 4; ++r) {
                red1[(g * 4 + r) * 4 + w] = s1[r];
                red2[(g * 4 + r) * 4 + w] = s2[r];
            }
        }
        __syncthreads();
#pragma unroll
        for (int n = 0; n < 4; ++n) {
            int c = w * 64 + n * 16 + lr;
            float gg = ln1g[c], bb = ln1b[c];
#pragma unroll
            for (int r = 0; r < 4; ++r) {
                int rr = g * 4 + r;
                float m1 = red1[rr * 4] + red1[rr * 4 + 1] + red1[rr * 4 + 2] + red1[rr * 4 + 3];
                float m2 = red2[rr * 4] + red2[rr * 4 + 1] + red2[rr * 4 + 2] + red2[rr * 4 + 3];
                float mu = m1 * (1.f / 256.f);
                float var = m2 * (1.f / 256.f) - mu * mu;
                float rstd = rsqrtf(var + 1e-5f);
                float o = (x1v[n][r] - mu) * rstd * gg + bb;
                x1v[n][r] = o;
                *(ushort*)(Asp + rr * 512 + ((2 * c) ^ ((rr & 7) << 4))) = f2bf(o);
            }
        }
    }

    // ---- P1a: FFN1 cols 0-255, 8 chunks ----
    WSTORE(0);
    WLOAD(W1t, 256, 0, 32);
    f32x4 acc1[4] = {};
#pragma unroll
    for (int c = 0; c < 8; ++c) {
        __syncthreads();
        short8 a = *(const short8*)(Asp + lr * 512 + ((c * 64 + g * 16) ^ sw_a));
#pragma unroll
        for (int n = 0; n < 4; ++n)
            acc1[n] = MFMA16(a, BFRAG(c & 1, w * 64 + n * 16 + lr), acc1[n]);
        if (c < 6)       { WSTORE((c + 1) & 1); WLOAD(W1t, 256, 0, (c + 2) * 32); }
        else if (c == 6) { WSTORE(1);           WLOAD(W1t, 256, 256, 0); }
    }
#pragma unroll
    for (int n = 0; n < 4; ++n) {
        int cf = w * 64 + n * 16 + lr;
        float bi = b1[cf];
#pragma unroll
        for (int r = 0; r < 4; ++r) {
            int rw = g * 4 + r;
            float v = fmaxf(acc1[n][r] + bi, 0.f);
            *(ushort*)(hidp + rw * 1024 + ((cf * 2) ^ ((rw & 7) << 4))) = f2bf(v);
        }
    }

    // ---- P1b: FFN1 cols 256-511, 8 chunks ----
    WSTORE(0);
    WLOAD(W1t, 256, 256, 32);
    f32x4 acc1b[4] = {};
#pragma unroll
    for (int c = 0; c < 8; ++c) {
        __syncthreads();
        short8 a = *(const short8*)(Asp + lr * 512 + ((c * 64 + g * 16) ^ sw_a));
#pragma unroll
        for (int n = 0; n < 4; ++n)
            acc1b[n] = MFMA16(a, BFRAG(c & 1, w * 64 + n * 16 + lr), acc1b[n]);
        if (c < 6)       { WSTORE((c + 1) & 1); WLOAD(W1t, 256, 256, (c + 2) * 32); }
        else if (c == 6) { WSTORE(1);           WLOAD(W2t, 512, 0, 0); }
    }
#pragma unroll
    for (int n = 0; n < 4; ++n) {
        int cf = 256 + w * 64 + n * 16 + lr;
        float bi = b1[cf];
#pragma unroll
        for (int r = 0; r < 4; ++r) {
            int rw = g * 4 + r;
            float v = fmaxf(acc1b[n][r] + bi, 0.f);
            *(ushort*)(hidp + rw * 1024 + ((cf * 2) ^ ((rw & 7) << 4))) = f2bf(v);
        }
    }

    // ---- P2: FFN2 (KD=512), 16 chunks, A = hidp ----
    WSTORE(0);
    WLOAD(W2t, 512, 0, 32);
    f32x4 acc2[4] = {};
#pragma unroll
    for (int c = 0; c < 16; ++c) {
        __syncthreads();
        short8 a = *(const short8*)(hidp + lr * 1024 + ((c * 64 + g * 16) ^ sw_a));
#pragma unroll
        for (int n = 0; n < 4; ++n)
            acc2[n] = MFMA16(a, BFRAG(c & 1, w * 64 + n * 16 + lr), acc2[n]);
        if (c < 14)       { WSTORE((c + 1) & 1); WLOAD(W2t, 512, 0, (c + 2) * 32); }
        else if (c == 14) { WSTORE(1);           WLOAD(WvN ? WvN : W2t, WvN ? 256 : 512, 0, 0); }
    }

    // ---- LN2 (resid = x1 regs) ----
#pragma unroll
    for (int n = 0; n < 4; ++n) {
        int c = w * 64 + n * 16 + lr;
        float bi = b2[c];
#pragma unroll
        for (int r = 0; r < 4; ++r)
            acc2[n][r] = acc2[n][r] + bi + x1v[n][r];
    }
    {
        float s1[4] = {0.f, 0.f, 0.f, 0.f}, s2[4] = {0.f, 0.f, 0.f, 0.f};
#pragma unroll
        for (int n = 0; n < 4; ++n)
#pragma unroll
            for (int r = 0; r < 4; ++r) {
                s1[r] += acc2[n][r];
                s2[r] += acc2[n][r] * acc2[n][r];
            }
#pragma unroll
        for (int off = 1; off < 16; off <<= 1) {
#pragma unroll
            for (int r = 0; r < 4; ++r) {
                s1[r] += __shfl_xor(s1[r], off, 64);
                s2[r] += __shfl_xor(s2[r], off, 64);
            }
        }
        if (lr == 0) {
#pragma unroll
            for (int r = 0; r < 4; ++r) {
                red1[(g * 4 + r) * 4 + w] = s1[r];
                red2[(g * 4 + r) * 4 + w] = s2[r];
            }
        }
        __syncthreads();
#pragma unroll
        for (int n = 0; n < 4; ++n) {
            int c = w * 64 + n * 16 + lr;
            float gg = ln2g[c], bb = ln2b[c];
#pragma unroll
            for (int r = 0; r < 4; ++r) {
                int rr = g * 4 + r;
                float m1 = red1[rr * 4] + red1[rr * 4 + 1] + red1[rr * 4 + 2] + red1[rr * 4 + 3];
                float m2 = red2[rr * 4] + red2[rr * 4 + 1] + red2[rr * 4 + 2] + red2[rr * 4 + 3];
                float mu = m1 * (1.f / 256.f);
                float var = m2 * (1.f / 256.f) - mu * mu;
                float rstd = rsqrtf(var + 1e-5f);
                int row = row0 + rr;
                float o = (acc2[n][r] - mu) * rstd * gg + bb;
                feats[(size_t)row * 256 + c] = o;
                ushort ob = f2bf(o);
                featsb[(size_t)row * 256 + c] = ob;
                *(ushort*)(Asp + rr * 512 + ((2 * c) ^ ((rr & 7) << 4))) = ob;
            }
        }
    }

    // ---- P3: V(l+1), 8 chunks, A = Asp(x2) ----
    if (WvN) {
        WSTORE(0);
        WLOAD(WvN, 256, 0, 32);
        f32x4 acc3[4] = {};
#pragma unroll
        for (int c = 0; c < 8; ++c) {
            __syncthreads();
            short8 a = *(const short8*)(Asp + lr * 512 + ((c * 64 + g * 16) ^ sw_a));
#pragma unroll
            for (int n = 0; n < 4; ++n)
                acc3[n] = MFMA16(a, BFRAG(c & 1, w * 64 + n * 16 + lr), acc3[n]);
            if (c < 6)       { WSTORE((c + 1) & 1); WLOAD(WvN, 256, 0, (c + 2) * 32); }
            else if (c == 6) { WSTORE(1); }
        }
        __syncthreads();
        ushort(*Ts)[24] = (ushort(*)[24])hidp;
#pragma unroll
        for (int n = 0; n < 4; ++n) {
            int c = w * 64 + n * 16 + lr;
            float bi = vbN[c];
#pragma unroll
            for (int r = 0; r < 4; ++r)
                Ts[c][g * 4 + r] = f2bf(acc3[n][r] + bi);
        }
        __syncthreads();
        {
            int c = t;
            int b = row0 >> 11;
            int n0 = row0 & 2047;
            ushort* dst = Vt + ((size_t)(b * 256 + c)) * 2048 + n0;
            *(uint4*)dst = *(uint4*)&Ts[c][0];
            *(uint4*)(dst + 8) = *(uint4*)&Ts[c][8];
        }
    }
}

// ---------------------------------------------------------------------------
extern "C" void kernel_launch(void* const* d_in, const int* in_sizes, int n_in,
                              void* d_out, int out_size, void* d_ws, size_t ws_size,
                              hipStream_t stream) {
    const float* lat    = (const float*)d_in[0];
    const float* xc     = (const float*)d_in[1];
    const float* emb    = (const float*)d_in[2];
    const float* in_W   = (const float*)d_in[3];
    const float* in_b   = (const float*)d_in[4];
    const float* val_W  = (const float*)d_in[5];
    const float* val_b  = (const float*)d_in[6];
    const float* attn_W = (const float*)d_in[7];
    const float* attn_b = (const float*)d_in[8];
    const float* ln1_g  = (const float*)d_in[9];
    const float* ln1_b  = (const float*)d_in[10];
    const float* ln2_g  = (const float*)d_in[11];
    const float* ln2_b  = (const float*)d_in[12];
    const float* ffn_W1 = (const float*)d_in[13];
    const float* ffn_b1 = (const float*)d_in[14];
    const float* ffn_W2 = (const float*)d_in[15];
    const float* ffn_b2 = (const float*)d_in[16];
    const float* out_W1 = (const float*)d_in[17];
    const float* out_b1 = (const float*)d_in[18];
    const float* out_W2 = (const float*)d_in[19];
    const float* out_b2 = (const float*)d_in[20];

    char* W = (char*)d_ws;
    float*  feats  = (float*)W;                                // 8 MB
    ushort* featsb = (ushort*)(W + (8u << 20));                // 4 MB
    ushort* attb   = (ushort*)(W + (12u << 20));               // 4 MB
    ushort* Vt     = (ushort*)(W + (16u << 20));               // 4 MB
    ushort* wp     = (ushort*)(W + (20u << 20));               // 3.2 MB
    ushort* E      = (ushort*)(W + (24u << 20));               // 128 MiB
    ushort* Wvt  = wp;
    ushort* Wat  = wp + 262144;
    ushort* W1t  = wp + 524288;
    ushort* W2t  = wp + 1048576;
    ushort* Wo1t = wp + 1572864;

    pack_weights<<<6400, 256, 0, stream>>>(val_W, attn_W, ffn_W1, ffn_W2, out_W1, wp);
    input_mlp<<<R_ / 8, 256, 0, stream>>>(xc, emb, lat, in_W, in_b, feats, featsb);
    ebuild<<<dim3(4, 32, B_), 256, 0, stream>>>(xc, E);

    gemmM<3><<<R_ / 16, 256, 0, stream>>>(
        featsb, Wvt, val_b, nullptr, nullptr, Vt, nullptr);

    for (int l = 0; l < LAYERS_; ++l) {
        pv_gemm<<<512, 256, 0, stream>>>(E, Vt, attb);
        const ushort* WvN = (l + 1 < LAYERS_) ? (Wvt + (l + 1) * 65536) : nullptr;
        const float* vbN = val_b + ((l + 1 < LAYERS_) ? (l + 1) * 256 : 0);
        gemm_layer<<<R_ / 16, 256, 0, stream>>>(
            attb, Wat + l * 65536, attn_b + l * 256,
            feats, ln1_g + l * 256, ln1_b + l * 256,
            W1t + l * 131072, ffn_b1 + l * 512,
            W2t + l * 131072, ffn_b2 + l * 256,
            ln2_g + l * 256, ln2_b + l * 256,
            featsb, WvN, vbN, Vt);
    }

    gemmM<4><<<R_ / 16, 256, 0, stream>>>(
        featsb, Wo1t, out_b1, out_W2, out_b2, nullptr, (float*)d_out);
}

// Round 13
// 272.821 us; speedup vs baseline: 1.3400x; 1.1373x over previous
//
#include <hip/hip_runtime.h>

#define B_ 4
#define N_ 2048
#define R_ (B_ * N_)      // 8192 rows
#define HID_ 256
#define EMB_ 64
#define IN_DIM_ 70
#define H_ 4
#define HEAD_ 64
#define FFN_ 512
#define LAYERS_ 4

typedef __attribute__((ext_vector_type(8))) short short8;
typedef __attribute__((ext_vector_type(4))) float f32x4;
typedef __attribute__((ext_vector_type(2))) float f32x2;
typedef unsigned short ushort;
typedef unsigned char uchar;

static __device__ __forceinline__ ushort f2bf(float f) {
    unsigned u = __builtin_bit_cast(unsigned, f);
    u += 0x7fffu + ((u >> 16) & 1u);   // RNE
    return (ushort)(u >> 16);
}
static __device__ __forceinline__ float bf2f(ushort u) {
    unsigned x = ((unsigned)u) << 16;
    return __builtin_bit_cast(float, x);
}

// 8 fp8(e4m3) bytes -> 8 bf16 (via f32), for MFMA A-fragments
static __device__ __forceinline__ short8 cvt8(uint2 u) {
    f32x2 f0 = __builtin_amdgcn_cvt_pk_f32_fp8(u.x, false);
    f32x2 f1 = __builtin_amdgcn_cvt_pk_f32_fp8(u.x, true);
    f32x2 f2 = __builtin_amdgcn_cvt_pk_f32_fp8(u.y, false);
    f32x2 f3 = __builtin_amdgcn_cvt_pk_f32_fp8(u.y, true);
    union { unsigned w[4]; short8 s; } pk;
    asm("v_cvt_pk_bf16_f32 %0, %1, %2" : "=v"(pk.w[0]) : "v"(f0[0]), "v"(f0[1]));
    asm("v_cvt_pk_bf16_f32 %0, %1, %2" : "=v"(pk.w[1]) : "v"(f1[0]), "v"(f1[1]));
    asm("v_cvt_pk_bf16_f32 %0, %1, %2" : "=v"(pk.w[2]) : "v"(f2[0]), "v"(f2[1]));
    asm("v_cvt_pk_bf16_f32 %0, %1, %2" : "=v"(pk.w[3]) : "v"(f3[0]), "v"(f3[1]));
    return pk.s;
}

#define GLOAD_LDS16(g, l)                                              \
    __builtin_amdgcn_global_load_lds(                                  \
        (const __attribute__((address_space(1))) void*)(g),            \
        (__attribute__((address_space(3))) void*)(l), 16, 0, 0)

#define MFMA16(a, b, c) __builtin_amdgcn_mfma_f32_16x16x32_bf16(a, b, c, 0, 0, 0)

// ---------------------------------------------------------------------------
// Pack all weights to bf16, transposed [c][k] layout.
// ---------------------------------------------------------------------------
__global__ __launch_bounds__(256) void pack_weights(const float* __restrict__ valW,
                                                    const float* __restrict__ attnW,
                                                    const float* __restrict__ ffnW1,
                                                    const float* __restrict__ ffnW2,
                                                    const float* __restrict__ outW1,
                                                    ushort* __restrict__ wp) {
    int idx = blockIdx.x * 256 + threadIdx.x;
    float v;
    if (idx < 262144) {
        int l = idx >> 16, c = (idx >> 8) & 255, k = idx & 255;
        v = valW[((l * 4 + (c >> 6)) * 256 + k) * 64 + (c & 63)];
    } else if (idx < 524288) {
        int i2 = idx - 262144;
        int l = i2 >> 16, c = (i2 >> 8) & 255, k = i2 & 255;
        v = attnW[l * 65536 + k * 256 + c];
    } else if (idx < 1048576) {
        int i2 = idx - 524288;
        int l = i2 >> 17, c = (i2 >> 8) & 511, k = i2 & 255;
        v = ffnW1[l * 131072 + k * 512 + c];
    } else if (idx < 1572864) {
        int i2 = idx - 1048576;
        int l = i2 >> 17, c = (i2 >> 9) & 255, k = i2 & 511;
        v = ffnW2[l * 131072 + k * 256 + c];
    } else {
        int i2 = idx - 1572864;
        int c = i2 >> 8, k = i2 & 255;
        v = outW1[k * 256 + c];
    }
    wp[idx] = f2bf(v);
}

// ---------------------------------------------------------------------------
// Input MLP: feats = relu(concat @ in_W + in_b); dual write fp32 + bf16
// ---------------------------------------------------------------------------
__global__ __launch_bounds__(256) void input_mlp(const float* __restrict__ xc,
                                                 const float* __restrict__ emb,
                                                 const float* __restrict__ lat,
                                                 const float* __restrict__ W,
                                                 const float* __restrict__ b,
                                                 float* __restrict__ feats,
                                                 ushort* __restrict__ featsb) {
    __shared__ float xr[8][IN_DIM_ + 2];
    int t = threadIdx.x;
    int row0 = blockIdx.x * 8;
    for (int idx = t; idx < 8 * IN_DIM_; idx += 256) {
        int r = idx / IN_DIM_, f = idx % IN_DIM_;
        int rr = row0 + r;
        float v;
        if (f < 3)       v = xc[rr * 3 + f];
        else if (f < 67) v = emb[rr * EMB_ + (f - 3)];
        else             v = lat[rr * 3 + (f - 67)];
        xr[r][f] = v;
    }
    __syncthreads();
    float acc[8] = {0.f, 0.f, 0.f, 0.f, 0.f, 0.f, 0.f, 0.f};
    for (int f = 0; f < IN_DIM_; ++f) {
        float w = W[f * HID_ + t];
#pragma unroll
        for (int r = 0; r < 8; ++r) acc[r] += xr[r][f] * w;
    }
    float bb = b[t];
#pragma unroll
    for (int r = 0; r < 8; ++r) {
        float v = fmaxf(acc[r] + bb, 0.f);
        feats[(row0 + r) * HID_ + t] = v;
        featsb[(row0 + r) * HID_ + t] = f2bf(v);
    }
}

// ---------------------------------------------------------------------------
// ebuild: E[h][b][i][j] fp8 e4m3, built once. Lane owns 8 consecutive j
// (uint2 8B stores). Block: 512 j x 64 i. Grid (4, 32, B). Writes 64 MB.
// ---------------------------------------------------------------------------
__global__ __launch_bounds__(256) void ebuild(const float* __restrict__ xc,
                                              uchar* __restrict__ E) {
    __shared__ float4 civ[64];
    __shared__ float4 cjv[512];
    int t = threadIdx.x;
    int jb = blockIdx.x;
    int ibl = blockIdx.y;
    int b = blockIdx.z;
    const float* xb = xc + (size_t)b * N_ * 3;
    if (t < 64) {
        const float* p = &xb[(ibl * 64 + t) * 3];
        float x = p[0], y = p[1], z = p[2];
        civ[t] = make_float4(x, y, z, x * x + y * y + z * z);
    }
#pragma unroll
    for (int s = 0; s < 2; ++s) {
        int j = s * 256 + t;
        const float* p = &xb[(jb * 512 + j) * 3];
        float x = p[0], y = p[1], z = p[2];
        cjv[j] = make_float4(x, y, z, x * x + y * y + z * z);
    }
    __syncthreads();
    int lane = t & 63, ig = t >> 6;
    float4 cj[8];
#pragma unroll
    for (int e = 0; e < 8; ++e) cj[e] = cjv[lane * 8 + e];
    const float ch0 = -4.f * 1.44269504088896f;
    uchar* Ebase = E + ((size_t)b * 2048 + ibl * 64) * 2048 + (size_t)jb * 512 + lane * 8;

    for (int r = 0; r < 16; ++r) {
        int i = ig * 16 + r;
        float4 ci = civ[i];
        float d[8];
#pragma unroll
        for (int e = 0; e < 8; ++e)
            d[e] = (ci.w + cj[e].w) -
                   2.f * (ci.x * cj[e].x + ci.y * cj[e].y + ci.z * cj[e].z);
        float ch = ch0;
#pragma unroll
        for (int h = 0; h < 4; ++h) {
            float ex[8];
#pragma unroll
            for (int e = 0; e < 8; ++e) ex[e] = exp2f(d[e] * ch);
            int lo = 0, hi = 0;
            lo = __builtin_amdgcn_cvt_pk_fp8_f32(ex[0], ex[1], lo, false);
            lo = __builtin_amdgcn_cvt_pk_fp8_f32(ex[2], ex[3], lo, true);
            hi = __builtin_amdgcn_cvt_pk_fp8_f32(ex[4], ex[5], hi, false);
            hi = __builtin_amdgcn_cvt_pk_fp8_f32(ex[6], ex[7], hi, true);
            uint2 val;
            val.x = (unsigned)lo;
            val.y = (unsigned)hi;
            *(uint2*)(Ebase + (size_t)h * 4 * 2048 * 2048 + (size_t)i * 2048) = val;
            ch *= 0.25f;
        }
    }
}

// ---------------------------------------------------------------------------
// pv_gemm (fp8-E): att[b,i,h*64+d] = (E[h,b,i,:] @ V) / rowsum(E).
// E fp8 direct global->reg (uint2, 1-chunk prefetch), converted in-register
// to bf16 fragments; V bf16 LDS-staged (4-wave reuse), dbuf, 1 bar/chunk.
// Numerator and denominator use the SAME converted fragments.
// ---------------------------------------------------------------------------
__global__ __launch_bounds__(256, 2) void pv_gemm(const uchar* __restrict__ E,
                                                  const ushort* __restrict__ Vt,
                                                  ushort* __restrict__ attb) {
    __shared__ __align__(16) char lds[16384];   // V dbuf 2x8KB
    int t = threadIdx.x;
    int l = t & 63, w = t >> 6;
    int lr = l & 15, g = l >> 4;

    int f = blockIdx.x;                 // 512 blocks
    int xcd = f & 7, s = f >> 3;
    int combo = xcd * 2 + (s >> 5);     // 0..15
    int ib = s & 31;
    int b = combo & 3, h = combo >> 2;
    int i_base = ib * 64;
    int hc = h * 64;

    const uchar* Eb = E + (size_t)(h * 4 + b) * 2048 * 2048;
    int slot = t & 7, trow = t >> 3;

    const ushort* srcB[2];
#pragma unroll
    for (int q = 0; q < 2; ++q) {
        int cl = q * 32 + trow;
        srcB[q] = Vt + (size_t)(b * 256 + hc + cl) * 2048 + ((slot ^ (cl & 7)) << 3);
    }
    auto STAGE = [&](int buf) {
#pragma unroll
        for (int q = 0; q < 2; ++q)
            GLOAD_LDS16(srcB[q], lds + buf * 8192 + q * 4096 + t * 16);
#pragma unroll
        for (int q = 0; q < 2; ++q) srcB[q] += 64;
    };

    f32x4 acc[4] = {};
    f32x4 accd = {};
    short8 ones = {0x3F80, 0x3F80, 0x3F80, 0x3F80, 0x3F80, 0x3F80, 0x3F80, 0x3F80};

    const uchar* ea = Eb + (size_t)(i_base + w * 16 + lr) * 2048 + g * 8;
    STAGE(0);
    uint2 ua0 = *(const uint2*)(ea);
    uint2 ua1 = *(const uint2*)(ea + 32);

    for (int c = 0; c < 32; ++c) {
        __syncthreads();
        if (c + 1 < 32) STAGE((c + 1) & 1);
        uint2 na0 = ua0, na1 = ua1;
        if (c + 1 < 32) {
            na0 = *(const uint2*)(ea + (c + 1) * 64);
            na1 = *(const uint2*)(ea + (c + 1) * 64 + 32);
        }
        short8 a0 = cvt8(ua0);
        short8 a1 = cvt8(ua1);
        const char* Bs = lds + (c & 1) * 8192;

        accd = MFMA16(a0, ones, accd);
        accd = MFMA16(a1, ones, accd);
#pragma unroll
        for (int n = 0; n < 4; ++n) {
            int cc = n * 16 + lr;
            const char* cb = Bs + cc * 128;
            int sw = (cc & 7) << 4;
            short8 b0 = *(const short8*)(cb + ((g * 16) ^ sw));
            short8 b1 = *(const short8*)(cb + ((64 + g * 16) ^ sw));
            acc[n] = MFMA16(a0, b0, acc[n]);
            acc[n] = MFMA16(a1, b1, acc[n]);
        }
        ua0 = na0; ua1 = na1;
    }

#pragma unroll
    for (int r = 0; r < 4; ++r) {
        float invd = 1.f / (accd[r] + 1e-8f);
        int row = i_base + w * 16 + g * 4 + r;
        size_t rb = ((size_t)b * N_ + row) * 256 + hc + lr;
#pragma unroll
        for (int n = 0; n < 4; ++n)
            attb[rb + n * 16] = f2bf(acc[n][r] * invd);
    }
}

// ---------------------------------------------------------------------------
// gemmM (R10): LDS-dbuf staged A+B, KD=256. MODE 3 / MODE 4.
// ---------------------------------------------------------------------------
template <int MODE>
__global__ __launch_bounds__(256) void gemmM(const ushort* __restrict__ A,
                                             const ushort* __restrict__ Bt,
                                             const float* __restrict__ bias,
                                             const float* __restrict__ resid,
                                             const float* __restrict__ lng,
                                             ushort* __restrict__ outb,
                                             float* __restrict__ outf) {
    __shared__ __align__(16) char lds[69632];
    int t = threadIdx.x;
    int l = t & 63, w = t >> 6;
    int lr = l & 15, g = l >> 4;
    int row0 = blockIdx.x * 16;
    f32x4 acc[4] = {};

    const ushort* srcA = A + (size_t)(row0 + (t >> 3)) * 256 + (((t & 7) ^ ((t >> 3) & 7)) << 3);
    const ushort* srcB[8];
#pragma unroll
    for (int q = 0; q < 8; ++q) {
        int cl = q * 32 + (t >> 3);
        srcB[q] = Bt + (size_t)cl * 256 + (((t & 7) ^ (cl & 7)) << 3);
    }
    auto STAGE = [&](int buf) {
        if (t < 128) GLOAD_LDS16(srcA, lds + buf * 2048 + t * 16);
#pragma unroll
        for (int q = 0; q < 8; ++q)
            GLOAD_LDS16(srcB[q], lds + 4096 + buf * 32768 + q * 4096 + t * 16);
        srcA += 64;
#pragma unroll
        for (int q = 0; q < 8; ++q) srcB[q] += 64;
    };

    int sw_a = (lr & 7) << 4;
    int aoff = lr * 128;

    STAGE(0);
#pragma unroll
    for (int c = 0; c < 4; ++c) {
        __syncthreads();
        if (c + 1 < 4) STAGE((c + 1) & 1);
        const char* As = lds + (c & 1) * 2048;
        const char* Ws = lds + 4096 + (c & 1) * 32768;

        short8 a0 = *(const short8*)(As + aoff + ((g * 16) ^ sw_a));
        short8 a1 = *(const short8*)(As + aoff + ((64 + g * 16) ^ sw_a));
#pragma unroll
        for (int n = 0; n < 4; ++n) {
            int cc = w * 64 + n * 16 + lr;
            const char* cb = Ws + cc * 128;
            int sw = (cc & 7) << 4;
            short8 b0 = *(const short8*)(cb + ((g * 16) ^ sw));
            short8 b1 = *(const short8*)(cb + ((64 + g * 16) ^ sw));
            acc[n] = MFMA16(a0, b0, acc[n]);
            acc[n] = MFMA16(a1, b1, acc[n]);
        }
    }
    __syncthreads();

    if constexpr (MODE == 3) {
        ushort(*Ts)[24] = (ushort(*)[24])lds;
#pragma unroll
        for (int n = 0; n < 4; ++n) {
            int c = w * 64 + n * 16 + lr;
            float bi = bias[c];
#pragma unroll
            for (int r = 0; r < 4; ++r)
                Ts[c][g * 4 + r] = f2bf(acc[n][r] + bi);
        }
        __syncthreads();
        {
            int c = t;
            int b = row0 >> 11;
            int n0 = row0 & 2047;
            ushort* dst = outb + ((size_t)(b * 256 + c)) * 2048 + n0;
            *(uint4*)dst = *(uint4*)&Ts[c][0];
            *(uint4*)(dst + 8) = *(uint4*)&Ts[c][8];
        }
    } else {  // MODE 4
        const float* W2 = resid;    // [256][3]
        const float* b2 = lng;      // [3]
        ushort(*Ts)[264] = (ushort(*)[264])lds;
#pragma unroll
        for (int n = 0; n < 4; ++n) {
            int c = w * 64 + n * 16 + lr;
            float bi = bias[c];
#pragma unroll
            for (int r = 0; r < 4; ++r)
                Ts[g * 4 + r][c] = f2bf(fmaxf(acc[n][r] + bi, 0.f));
        }
        __syncthreads();
        int row = t >> 4, sg = t & 15;
        float p0 = 0.f, p1 = 0.f, p2 = 0.f;
#pragma unroll
        for (int e = 0; e < 16; ++e) {
            float x = bf2f(Ts[row][sg * 16 + e]);
            const float* wr = &W2[(sg * 16 + e) * 3];
            p0 += x * wr[0];
            p1 += x * wr[1];
            p2 += x * wr[2];
        }
#pragma unroll
        for (int off = 1; off < 16; off <<= 1) {
            p0 += __shfl_xor(p0, off, 64);
            p1 += __shfl_xor(p1, off, 64);
            p2 += __shfl_xor(p2, off, 64);
        }
        if (sg == 0) {
            int gr = row0 + row;
            outf[gr * 3 + 0] = p0 + b2[0];
            outf[gr * 3 + 1] = p1 + b2[1];
            outf[gr * 3 + 2] = p2 + b2[2];
        }
    }
}

// ---------------------------------------------------------------------------
// gemm_layer (R10 revert): attn-proj -> LN1 -> FFN1 -> ReLU -> FFN2 -> LN2
// -> V(l+1). Weights stream via reg-dbuf (WLOADG under compute, WSTORE after
// barrier). LDS: Aa 4K | Asp 8K | Wsp 32K | hid 16K = 60KB.
// ---------------------------------------------------------------------------
__global__ __launch_bounds__(256) void gemm_layer(
        const ushort* __restrict__ attb,
        const ushort* __restrict__ Wat, const float* __restrict__ pb,
        float* __restrict__ feats,
        const float* __restrict__ ln1g, const float* __restrict__ ln1b,
        const ushort* __restrict__ W1t, const float* __restrict__ b1,
        const ushort* __restrict__ W2t, const float* __restrict__ b2,
        const float* __restrict__ ln2g, const float* __restrict__ ln2b,
        ushort* __restrict__ featsb,
        const ushort* __restrict__ WvN, const float* __restrict__ vbN,
        ushort* __restrict__ Vt) {
    __shared__ __align__(16) char lds[61440];
    char* Aa = lds;             // 4KB (2 bufs); red1/red2 overlay after P0
    char* Asp = lds + 4096;     // 8KB: x1 bf16, later x2 bf16
    char* Wsp = lds + 12288;    // 32KB
    char* hidp = lds + 45056;   // 16KB; Ts overlays in P3

    int t = threadIdx.x;
    int l = t & 63, w = t >> 6;
    int lr = l & 15, g = l >> 4;
    int row0 = blockIdx.x * 16;
    int sw_a = (lr & 7) << 4;
    int trow = t >> 3, slot = t & 7;

    uint4 wr0, wr1, wr2, wr3, wr4, wr5, wr6, wr7;
    auto WLOADG = [&](const ushort* Wb, int stride, int colbase, int c) {
        const ushort* base = Wb + c * 64;
#pragma unroll
        for (int q = 0; q < 8; ++q) {
            int cl = colbase + q * 32 + trow;
            uint4 v = *(const uint4*)(base + (size_t)cl * stride + ((slot ^ (cl & 7)) << 3));
            if (q == 0) wr0 = v; else if (q == 1) wr1 = v; else if (q == 2) wr2 = v;
            else if (q == 3) wr3 = v; else if (q == 4) wr4 = v; else if (q == 5) wr5 = v;
            else if (q == 6) wr6 = v; else wr7 = v;
        }
    };
    auto WSTORE = [&]() {
        *(uint4*)(Wsp + 0 * 4096 + t * 16) = wr0;
        *(uint4*)(Wsp + 1 * 4096 + t * 16) = wr1;
        *(uint4*)(Wsp + 2 * 4096 + t * 16) = wr2;
        *(uint4*)(Wsp + 3 * 4096 + t * 16) = wr3;
        *(uint4*)(Wsp + 4 * 4096 + t * 16) = wr4;
        *(uint4*)(Wsp + 5 * 4096 + t * 16) = wr5;
        *(uint4*)(Wsp + 6 * 4096 + t * 16) = wr6;
        *(uint4*)(Wsp + 7 * 4096 + t * 16) = wr7;
    };

    // ---- P0: attn-proj (KD=256), A = attb staged, W = Wat reg-dbuf ----
    const ushort* srcA = attb + (size_t)(row0 + trow) * 256 + ((slot ^ (trow & 7)) << 3);
    auto STAGEA = [&](int buf, int c) {
        if (t < 128) GLOAD_LDS16(srcA + c * 64, Aa + buf * 2048 + t * 16);
    };

    f32x4 acc[4] = {};
    STAGEA(0, 0);
    WLOADG(Wat, 256, 0, 0);
#pragma unroll
    for (int c = 0; c < 4; ++c) {
        __syncthreads();            // Aa[c&1] drained; Wsp free
        WSTORE();
        __syncthreads();            // Wsp visible
        if (c < 3) { WLOADG(Wat, 256, 0, c + 1); STAGEA((c + 1) & 1, c + 1); }
        else WLOADG(W1t, 256, 0, 0);    // prefetch P1 first chunk

        const char* As = Aa + (c & 1) * 2048;
        short8 a0 = *(const short8*)(As + lr * 128 + ((g * 16) ^ sw_a));
        short8 a1 = *(const short8*)(As + lr * 128 + ((64 + g * 16) ^ sw_a));
#pragma unroll
        for (int n = 0; n < 4; ++n) {
            int cc = w * 64 + n * 16 + lr;
            const char* cb = Wsp + cc * 128;
            int sw = (cc & 7) << 4;
            short8 b0 = *(const short8*)(cb + ((g * 16) ^ sw));
            short8 b1 = *(const short8*)(cb + ((64 + g * 16) ^ sw));
            acc[n] = MFMA16(a0, b0, acc[n]);
            acc[n] = MFMA16(a1, b1, acc[n]);
        }
    }
    __syncthreads();

    // ---- LN1 (x1 kept in regs; bf16 to Asp) ----
    float* red1 = (float*)lds;
    float* red2 = (float*)(lds + 512);
    float x1v[4][4];
    {
        float s1[4] = {0.f, 0.f, 0.f, 0.f}, s2[4] = {0.f, 0.f, 0.f, 0.f};
#pragma unroll
        for (int n = 0; n < 4; ++n) {
            int c = w * 64 + n * 16 + lr;
            float bi = pb[c];
#pragma unroll
            for (int r = 0; r < 4; ++r) {
                int row = row0 + g * 4 + r;
                float v = acc[n][r] + bi + feats[(size_t)row * 256 + c];
                x1v[n][r] = v;
                s1[r] += v;
                s2[r] += v * v;
            }
        }
#pragma unroll
        for (int off = 1; off < 16; off <<= 1) {
#pragma unroll
            for (int r = 0; r < 4; ++r) {
                s1[r] += __shfl_xor(s1[r], off, 64);
                s2[r] += __shfl_xor(s2[r], off, 64);
            }
        }
        if (lr == 0) {
#pragma unroll
            for (int r = 0; r < 4; ++r) {
                red1[(g * 4 + r) * 4 + w] = s1[r];
                red2[(g * 4 + r) * 4 + w] = s2[r];
            }
        }
        __syncthreads();
#pragma unroll
        for (int n = 0; n < 4; ++n) {
            int c = w * 64 + n * 16 + lr;
            float gg = ln1g[c], bb = ln1b[c];
#pragma unroll
            for (int r = 0; r < 4; ++r) {
                int rr = g * 4 + r;
                float m1 = red1[rr * 4] + red1[rr * 4 + 1] + red1[rr * 4 + 2] + red1[rr * 4 + 3];
                float m2 = red2[rr * 4] + red2[rr * 4 + 1] + red2[rr * 4 + 2] + red2[rr * 4 + 3];
                float mu = m1 * (1.f / 256.f);
                float var = m2 * (1.f / 256.f) - mu * mu;
                float rstd = rsqrtf(var + 1e-5f);
                float o = (x1v[n][r] - mu) * rstd * gg + bb;
                x1v[n][r] = o;                       // x1 (resid for LN2)
                *(ushort*)(Asp + rr * 512 + ((2 * c) ^ ((rr & 7) << 4))) = f2bf(o);
            }
        }
    }

    // ---- P1: FFN1 (KD=256, COLS=512), A = Asp, relu -> hid LDS ----
#pragma unroll
    for (int ch = 0; ch < 2; ++ch) {
        f32x4 acc1[4] = {};
#pragma unroll
        for (int c = 0; c < 4; ++c) {
            __syncthreads();
            WSTORE();
            __syncthreads();
            if (c < 3) WLOADG(W1t, 256, ch * 256, c + 1);
            else if (ch == 0) WLOADG(W1t, 256, 256, 0);
            else WLOADG(W2t, 512, 0, 0);

            short8 a0 = *(const short8*)(Asp + lr * 512 + ((c * 128 + g * 16) ^ sw_a));
            short8 a1 = *(const short8*)(Asp + lr * 512 + ((c * 128 + 64 + g * 16) ^ sw_a));
#pragma unroll
            for (int n = 0; n < 4; ++n) {
                int cc = w * 64 + n * 16 + lr;
                const char* cb = Wsp + cc * 128;
                int sw = (cc & 7) << 4;
                short8 b0 = *(const short8*)(cb + ((g * 16) ^ sw));
                short8 b1 = *(const short8*)(cb + ((64 + g * 16) ^ sw));
                acc1[n] = MFMA16(a0, b0, acc1[n]);
                acc1[n] = MFMA16(a1, b1, acc1[n]);
            }
        }
#pragma unroll
        for (int n = 0; n < 4; ++n) {
            int c = w * 64 + n * 16 + lr;
            float bi = b1[ch * 256 + c];
#pragma unroll
            for (int r = 0; r < 4; ++r) {
                int rw = g * 4 + r;
                float v = fmaxf(acc1[n][r] + bi, 0.f);
                int byte = rw * 1024 + (((ch * 256 + c) * 2) ^ ((rw & 7) << 4));
                *(ushort*)(hidp + byte) = f2bf(v);
            }
        }
    }

    // ---- P2: FFN2 (KD=512), A = hid LDS ----
    f32x4 acc2[4] = {};
#pragma unroll
    for (int c = 0; c < 8; ++c) {
        __syncthreads();
        WSTORE();
        __syncthreads();
        if (c < 7) WLOADG(W2t, 512, 0, c + 1);
        else if (WvN) WLOADG(WvN, 256, 0, 0);

        short8 a0 = *(const short8*)(hidp + lr * 1024 + ((c * 128 + g * 16) ^ sw_a));
        short8 a1 = *(const short8*)(hidp + lr * 1024 + ((c * 128 + 64 + g * 16) ^ sw_a));
#pragma unroll
        for (int n = 0; n < 4; ++n) {
            int cc = w * 64 + n * 16 + lr;
            const char* cb = Wsp + cc * 128;
            int sw = (cc & 7) << 4;
            short8 b0 = *(const short8*)(cb + ((g * 16) ^ sw));
            short8 b1 = *(const short8*)(cb + ((64 + g * 16) ^ sw));
            acc2[n] = MFMA16(a0, b0, acc2[n]);
            acc2[n] = MFMA16(a1, b1, acc2[n]);
        }
    }
    __syncthreads();

    // ---- LN2 (resid = x1 regs) -> feats fp32+bf16 global; x2 bf16 -> Asp ----
#pragma unroll
    for (int n = 0; n < 4; ++n) {
        int c = w * 64 + n * 16 + lr;
        float bi = b2[c];
#pragma unroll
        for (int r = 0; r < 4; ++r) {
            float v = acc2[n][r] + bi + x1v[n][r];
            acc2[n][r] = v;
        }
    }
    {
        float s1[4] = {0.f, 0.f, 0.f, 0.f}, s2[4] = {0.f, 0.f, 0.f, 0.f};
#pragma unroll
        for (int n = 0; n < 4; ++n)
#pragma unroll
            for (int r = 0; r < 4; ++r) {
                s1[r] += acc2[n][r];
                s2[r] += acc2[n][r] * acc2[n][r];
            }
#pragma unroll
        for (int off = 1; off < 16; off <<= 1) {
#pragma unroll
            for (int r = 0; r < 4; ++r) {
                s1[r] += __shfl_xor(s1[r], off, 64);
                s2[r] += __shfl_xor(s2[r], off, 64);
            }
        }
        if (lr == 0) {
#pragma unroll
            for (int r = 0; r < 4; ++r) {
                red1[(g * 4 + r) * 4 + w] = s1[r];
                red2[(g * 4 + r) * 4 + w] = s2[r];
            }
        }
        __syncthreads();
#pragma unroll
        for (int n = 0; n < 4; ++n) {
            int c = w * 64 + n * 16 + lr;
            float gg = ln2g[c], bb = ln2b[c];
#pragma unroll
            for (int r = 0; r < 4; ++r) {
                int rr = g * 4 + r;
                float m1 = red1[rr * 4] + red1[rr * 4 + 1] + red1[rr * 4 + 2] + red1[rr * 4 + 3];
                float m2 = red2[rr * 4] + red2[rr * 4 + 1] + red2[rr * 4 + 2] + red2[rr * 4 + 3];
                float mu = m1 * (1.f / 256.f);
                float var = m2 * (1.f / 256.f) - mu * mu;
                float rstd = rsqrtf(var + 1e-5f);
                int row = row0 + rr;
                float o = (acc2[n][r] - mu) * rstd * gg + bb;
                feats[(size_t)row * 256 + c] = o;
                ushort ob = f2bf(o);
                featsb[(size_t)row * 256 + c] = ob;
                *(ushort*)(Asp + rr * 512 + ((2 * c) ^ ((rr & 7) << 4))) = ob;
            }
        }
    }

    // ---- P3: V(l+1) = x2 @ WvN (KD=256), transposed bf16 -> Vt ----
    if (WvN) {
        f32x4 acc3[4] = {};
#pragma unroll
        for (int c = 0; c < 4; ++c) {
            __syncthreads();
            WSTORE();
            __syncthreads();
            if (c < 3) WLOADG(WvN, 256, 0, c + 1);

            short8 a0 = *(const short8*)(Asp + lr * 512 + ((c * 128 + g * 16) ^ sw_a));
            short8 a1 = *(const short8*)(Asp + lr * 512 + ((c * 128 + 64 + g * 16) ^ sw_a));
#pragma unroll
            for (int n = 0; n < 4; ++n) {
                int cc = w * 64 + n * 16 + lr;
                const char* cb = Wsp + cc * 128;
                int sw = (cc & 7) << 4;
                short8 b0 = *(const short8*)(cb + ((g * 16) ^ sw));
                short8 b1 = *(const short8*)(cb + ((64 + g * 16) ^ sw));
                acc3[n] = MFMA16(a0, b0, acc3[n]);
                acc3[n] = MFMA16(a1, b1, acc3[n]);
            }
        }
        __syncthreads();
        ushort(*Ts)[24] = (ushort(*)[24])hidp;   // 12KB <= 16KB
#pragma unroll
        for (int n = 0; n < 4; ++n) {
            int c = w * 64 + n * 16 + lr;
            float bi = vbN[c];
#pragma unroll
            for (int r = 0; r < 4; ++r)
                Ts[c][g * 4 + r] = f2bf(acc3[n][r] + bi);
        }
        __syncthreads();
        {
            int c = t;
            int b = row0 >> 11;
            int n0 = row0 & 2047;
            ushort* dst = Vt + ((size_t)(b * 256 + c)) * 2048 + n0;
            *(uint4*)dst = *(uint4*)&Ts[c][0];
            *(uint4*)(dst + 8) = *(uint4*)&Ts[c][8];
        }
    }
}

// ---------------------------------------------------------------------------
extern "C" void kernel_launch(void* const* d_in, const int* in_sizes, int n_in,
                              void* d_out, int out_size, void* d_ws, size_t ws_size,
                              hipStream_t stream) {
    const float* lat    = (const float*)d_in[0];
    const float* xc     = (const float*)d_in[1];
    const float* emb    = (const float*)d_in[2];
    const float* in_W   = (const float*)d_in[3];
    const float* in_b   = (const float*)d_in[4];
    const float* val_W  = (const float*)d_in[5];
    const float* val_b  = (const float*)d_in[6];
    const float* attn_W = (const float*)d_in[7];
    const float* attn_b = (const float*)d_in[8];
    const float* ln1_g  = (const float*)d_in[9];
    const float* ln1_b  = (const float*)d_in[10];
    const float* ln2_g  = (const float*)d_in[11];
    const float* ln2_b  = (const float*)d_in[12];
    const float* ffn_W1 = (const float*)d_in[13];
    const float* ffn_b1 = (const float*)d_in[14];
    const float* ffn_W2 = (const float*)d_in[15];
    const float* ffn_b2 = (const float*)d_in[16];
    const float* out_W1 = (const float*)d_in[17];
    const float* out_b1 = (const float*)d_in[18];
    const float* out_W2 = (const float*)d_in[19];
    const float* out_b2 = (const float*)d_in[20];

    char* W = (char*)d_ws;
    float*  feats  = (float*)W;                                // 8 MB
    ushort* featsb = (ushort*)(W + (8u << 20));                // 4 MB
    ushort* attb   = (ushort*)(W + (12u << 20));               // 4 MB
    ushort* Vt     = (ushort*)(W + (16u << 20));               // 4 MB
    ushort* wp     = (ushort*)(W + (20u << 20));               // 3.2 MB
    uchar*  E8     = (uchar*)(W + (24u << 20));                // 64 MiB fp8
    ushort* Wvt  = wp;
    ushort* Wat  = wp + 262144;
    ushort* W1t  = wp + 524288;
    ushort* W2t  = wp + 1048576;
    ushort* Wo1t = wp + 1572864;

    pack_weights<<<6400, 256, 0, stream>>>(val_W, attn_W, ffn_W1, ffn_W2, out_W1, wp);
    input_mlp<<<R_ / 8, 256, 0, stream>>>(xc, emb, lat, in_W, in_b, feats, featsb);
    ebuild<<<dim3(4, 32, B_), 256, 0, stream>>>(xc, E8);

    gemmM<3><<<R_ / 16, 256, 0, stream>>>(
        featsb, Wvt, val_b, nullptr, nullptr, Vt, nullptr);

    for (int l = 0; l < LAYERS_; ++l) {
        pv_gemm<<<512, 256, 0, stream>>>(E8, Vt, attb);
        const ushort* WvN = (l + 1 < LAYERS_) ? (Wvt + (l + 1) * 65536) : nullptr;
        const float* vbN = val_b + ((l + 1 < LAYERS_) ? (l + 1) * 256 : 0);
        gemm_layer<<<R_ / 16, 256, 0, stream>>>(
            attb, Wat + l * 65536, attn_b + l * 256,
            feats, ln1_g + l * 256, ln1_b + l * 256,
            W1t + l * 131072, ffn_b1 + l * 512,
            W2t + l * 131072, ffn_b2 + l * 256,
            ln2_g + l * 256, ln2_b + l * 256,
            featsb, WvN, vbN, Vt);
    }

    gemmM<4><<<R_ / 16, 256, 0, stream>>>(
        featsb, Wo1t, out_b1, out_W2, out_b2, nullptr, (float*)d_out);
}

// Round 14
// 268.969 us; speedup vs baseline: 1.3591x; 1.0143x over previous
//
#include <hip/hip_runtime.h>

#define B_ 4
#define N_ 2048
#define R_ (B_ * N_)      // 8192 rows
#define HID_ 256
#define EMB_ 64
#define IN_DIM_ 70
#define H_ 4
#define HEAD_ 64
#define FFN_ 512
#define LAYERS_ 4

typedef __attribute__((ext_vector_type(8))) short short8;
typedef __attribute__((ext_vector_type(4))) float f32x4;
typedef __attribute__((ext_vector_type(2))) float f32x2;
typedef unsigned short ushort;
typedef unsigned char uchar;

static __device__ __forceinline__ ushort f2bf(float f) {
    unsigned u = __builtin_bit_cast(unsigned, f);
    u += 0x7fffu + ((u >> 16) & 1u);   // RNE
    return (ushort)(u >> 16);
}
static __device__ __forceinline__ float bf2f(ushort u) {
    unsigned x = ((unsigned)u) << 16;
    return __builtin_bit_cast(float, x);
}

// 8 fp8(e4m3) bytes -> 8 bf16 (via f32), for MFMA A-fragments
static __device__ __forceinline__ short8 cvt8(uint2 u) {
    f32x2 f0 = __builtin_amdgcn_cvt_pk_f32_fp8(u.x, false);
    f32x2 f1 = __builtin_amdgcn_cvt_pk_f32_fp8(u.x, true);
    f32x2 f2 = __builtin_amdgcn_cvt_pk_f32_fp8(u.y, false);
    f32x2 f3 = __builtin_amdgcn_cvt_pk_f32_fp8(u.y, true);
    union { unsigned w[4]; short8 s; } pk;
    asm("v_cvt_pk_bf16_f32 %0, %1, %2" : "=v"(pk.w[0]) : "v"(f0[0]), "v"(f0[1]));
    asm("v_cvt_pk_bf16_f32 %0, %1, %2" : "=v"(pk.w[1]) : "v"(f1[0]), "v"(f1[1]));
    asm("v_cvt_pk_bf16_f32 %0, %1, %2" : "=v"(pk.w[2]) : "v"(f2[0]), "v"(f2[1]));
    asm("v_cvt_pk_bf16_f32 %0, %1, %2" : "=v"(pk.w[3]) : "v"(f3[0]), "v"(f3[1]));
    return pk.s;
}

#define GLOAD_LDS16(g, l)                                              \
    __builtin_amdgcn_global_load_lds(                                  \
        (const __attribute__((address_space(1))) void*)(g),            \
        (__attribute__((address_space(3))) void*)(l), 16, 0, 0)

#define MFMA16(a, b, c) __builtin_amdgcn_mfma_f32_16x16x32_bf16(a, b, c, 0, 0, 0)

// ---------------------------------------------------------------------------
// Pack all weights to bf16, transposed [c][k] layout.
// ---------------------------------------------------------------------------
__global__ __launch_bounds__(256) void pack_weights(const float* __restrict__ valW,
                                                    const float* __restrict__ attnW,
                                                    const float* __restrict__ ffnW1,
                                                    const float* __restrict__ ffnW2,
                                                    const float* __restrict__ outW1,
                                                    ushort* __restrict__ wp) {
    int idx = blockIdx.x * 256 + threadIdx.x;
    float v;
    if (idx < 262144) {
        int l = idx >> 16, c = (idx >> 8) & 255, k = idx & 255;
        v = valW[((l * 4 + (c >> 6)) * 256 + k) * 64 + (c & 63)];
    } else if (idx < 524288) {
        int i2 = idx - 262144;
        int l = i2 >> 16, c = (i2 >> 8) & 255, k = i2 & 255;
        v = attnW[l * 65536 + k * 256 + c];
    } else if (idx < 1048576) {
        int i2 = idx - 524288;
        int l = i2 >> 17, c = (i2 >> 8) & 511, k = i2 & 255;
        v = ffnW1[l * 131072 + k * 512 + c];
    } else if (idx < 1572864) {
        int i2 = idx - 1048576;
        int l = i2 >> 17, c = (i2 >> 9) & 255, k = i2 & 511;
        v = ffnW2[l * 131072 + k * 256 + c];
    } else {
        int i2 = idx - 1572864;
        int c = i2 >> 8, k = i2 & 255;
        v = outW1[k * 256 + c];
    }
    wp[idx] = f2bf(v);
}

// ---------------------------------------------------------------------------
// Input MLP: feats = relu(concat @ in_W + in_b); dual write fp32 + bf16
// ---------------------------------------------------------------------------
__global__ __launch_bounds__(256) void input_mlp(const float* __restrict__ xc,
                                                 const float* __restrict__ emb,
                                                 const float* __restrict__ lat,
                                                 const float* __restrict__ W,
                                                 const float* __restrict__ b,
                                                 float* __restrict__ feats,
                                                 ushort* __restrict__ featsb) {
    __shared__ float xr[8][IN_DIM_ + 2];
    int t = threadIdx.x;
    int row0 = blockIdx.x * 8;
    for (int idx = t; idx < 8 * IN_DIM_; idx += 256) {
        int r = idx / IN_DIM_, f = idx % IN_DIM_;
        int rr = row0 + r;
        float v;
        if (f < 3)       v = xc[rr * 3 + f];
        else if (f < 67) v = emb[rr * EMB_ + (f - 3)];
        else             v = lat[rr * 3 + (f - 67)];
        xr[r][f] = v;
    }
    __syncthreads();
    float acc[8] = {0.f, 0.f, 0.f, 0.f, 0.f, 0.f, 0.f, 0.f};
    for (int f = 0; f < IN_DIM_; ++f) {
        float w = W[f * HID_ + t];
#pragma unroll
        for (int r = 0; r < 8; ++r) acc[r] += xr[r][f] * w;
    }
    float bb = b[t];
#pragma unroll
    for (int r = 0; r < 8; ++r) {
        float v = fmaxf(acc[r] + bb, 0.f);
        feats[(row0 + r) * HID_ + t] = v;
        featsb[(row0 + r) * HID_ + t] = f2bf(v);
    }
}

// ---------------------------------------------------------------------------
// ebuild: E[h][b][i][j] fp8 e4m3, built once (unchanged from R13).
// ---------------------------------------------------------------------------
__global__ __launch_bounds__(256) void ebuild(const float* __restrict__ xc,
                                              uchar* __restrict__ E) {
    __shared__ float4 civ[64];
    __shared__ float4 cjv[512];
    int t = threadIdx.x;
    int jb = blockIdx.x;
    int ibl = blockIdx.y;
    int b = blockIdx.z;
    const float* xb = xc + (size_t)b * N_ * 3;
    if (t < 64) {
        const float* p = &xb[(ibl * 64 + t) * 3];
        float x = p[0], y = p[1], z = p[2];
        civ[t] = make_float4(x, y, z, x * x + y * y + z * z);
    }
#pragma unroll
    for (int s = 0; s < 2; ++s) {
        int j = s * 256 + t;
        const float* p = &xb[(jb * 512 + j) * 3];
        float x = p[0], y = p[1], z = p[2];
        cjv[j] = make_float4(x, y, z, x * x + y * y + z * z);
    }
    __syncthreads();
    int lane = t & 63, ig = t >> 6;
    float4 cj[8];
#pragma unroll
    for (int e = 0; e < 8; ++e) cj[e] = cjv[lane * 8 + e];
    const float ch0 = -4.f * 1.44269504088896f;
    uchar* Ebase = E + ((size_t)b * 2048 + ibl * 64) * 2048 + (size_t)jb * 512 + lane * 8;

    for (int r = 0; r < 16; ++r) {
        int i = ig * 16 + r;
        float4 ci = civ[i];
        float d[8];
#pragma unroll
        for (int e = 0; e < 8; ++e)
            d[e] = (ci.w + cj[e].w) -
                   2.f * (ci.x * cj[e].x + ci.y * cj[e].y + ci.z * cj[e].z);
        float ch = ch0;
#pragma unroll
        for (int h = 0; h < 4; ++h) {
            float ex[8];
#pragma unroll
            for (int e = 0; e < 8; ++e) ex[e] = exp2f(d[e] * ch);
            int lo = 0, hi = 0;
            lo = __builtin_amdgcn_cvt_pk_fp8_f32(ex[0], ex[1], lo, false);
            lo = __builtin_amdgcn_cvt_pk_fp8_f32(ex[2], ex[3], lo, true);
            hi = __builtin_amdgcn_cvt_pk_fp8_f32(ex[4], ex[5], hi, false);
            hi = __builtin_amdgcn_cvt_pk_fp8_f32(ex[6], ex[7], hi, true);
            uint2 val;
            val.x = (unsigned)lo;
            val.y = (unsigned)hi;
            *(uint2*)(Ebase + (size_t)h * 4 * 2048 * 2048 + (size_t)i * 2048) = val;
            ch *= 0.25f;
        }
    }
}

// ---------------------------------------------------------------------------
// pv_gemm: fp8 E staged via LDS in 128B-per-row PAIRS (2 K-chunks/stage,
// full-line coalesced source, pre-swizzled slot^(row&7)); cvt8 in-register;
// V bf16 LDS dbuf (unchanged). 1 barrier/chunk.
// ---------------------------------------------------------------------------
__global__ __launch_bounds__(256, 2) void pv_gemm(const uchar* __restrict__ E,
                                                  const ushort* __restrict__ Vt,
                                                  ushort* __restrict__ attb) {
    __shared__ __align__(16) char lds[32768];   // V dbuf 2x8KB @0 | E dbuf 2x8KB @16384
    int t = threadIdx.x;
    int l = t & 63, w = t >> 6;
    int lr = l & 15, g = l >> 4;

    int f = blockIdx.x;                 // 512 blocks
    int xcd = f & 7, s = f >> 3;
    int combo = xcd * 2 + (s >> 5);     // 0..15
    int ib = s & 31;
    int b = combo & 3, h = combo >> 2;
    int i_base = ib * 64;
    int hc = h * 64;

    const uchar* Eb = E + (size_t)(h * 4 + b) * 2048 * 2048;
    int slot = t & 7, trow = t >> 3;

    const ushort* srcB[2];
    const uchar* srcE[2];
#pragma unroll
    for (int q = 0; q < 2; ++q) {
        int cl = q * 32 + trow;
        srcB[q] = Vt + (size_t)(b * 256 + hc + cl) * 2048 + ((slot ^ (cl & 7)) << 3);
        srcE[q] = Eb + (size_t)(i_base + cl) * 2048 + ((slot ^ (cl & 7)) << 4);
    }
    auto STAGEV = [&](int buf) {
#pragma unroll
        for (int q = 0; q < 2; ++q)
            GLOAD_LDS16(srcB[q], lds + buf * 8192 + q * 4096 + t * 16);
#pragma unroll
        for (int q = 0; q < 2; ++q) srcB[q] += 64;
    };
    auto STAGEE = [&](int buf, int cpair) {
#pragma unroll
        for (int q = 0; q < 2; ++q)
            GLOAD_LDS16(srcE[q] + cpair * 128, lds + 16384 + buf * 8192 + q * 4096 + t * 16);
    };

    f32x4 acc[4] = {};
    f32x4 accd = {};
    short8 ones = {0x3F80, 0x3F80, 0x3F80, 0x3F80, 0x3F80, 0x3F80, 0x3F80, 0x3F80};

    int row = w * 16 + lr;
    int esw = (row & 7) << 4;
    int erow = row * 128;

    STAGEV(0);
    STAGEE(0, 0);

    for (int c = 0; c < 32; ++c) {
        __syncthreads();
        if (c + 1 < 32) STAGEV((c + 1) & 1);
        if ((c & 1) == 0 && c + 2 < 32) STAGEE(((c >> 1) + 1) & 1, (c >> 1) + 1);

        const char* Es = lds + 16384 + ((c >> 1) & 1) * 8192;
        int pbase = (c & 1) * 64;
        uint2 ua0 = *(const uint2*)(Es + erow + ((pbase + g * 8) ^ esw));
        uint2 ua1 = *(const uint2*)(Es + erow + ((pbase + 32 + g * 8) ^ esw));
        short8 a0 = cvt8(ua0);
        short8 a1 = cvt8(ua1);
        const char* Bs = lds + (c & 1) * 8192;

        accd = MFMA16(a0, ones, accd);
        accd = MFMA16(a1, ones, accd);
#pragma unroll
        for (int n = 0; n < 4; ++n) {
            int cc = n * 16 + lr;
            const char* cb = Bs + cc * 128;
            int sw = (cc & 7) << 4;
            short8 b0 = *(const short8*)(cb + ((g * 16) ^ sw));
            short8 b1 = *(const short8*)(cb + ((64 + g * 16) ^ sw));
            acc[n] = MFMA16(a0, b0, acc[n]);
            acc[n] = MFMA16(a1, b1, acc[n]);
        }
    }

#pragma unroll
    for (int r = 0; r < 4; ++r) {
        float invd = 1.f / (accd[r] + 1e-8f);
        int orow = i_base + w * 16 + g * 4 + r;
        size_t rb = ((size_t)b * N_ + orow) * 256 + hc + lr;
#pragma unroll
        for (int n = 0; n < 4; ++n)
            attb[rb + n * 16] = f2bf(acc[n][r] * invd);
    }
}

// ---------------------------------------------------------------------------
// gemmM (R10): LDS-dbuf staged A+B, KD=256. MODE 3 / MODE 4.
// ---------------------------------------------------------------------------
template <int MODE>
__global__ __launch_bounds__(256) void gemmM(const ushort* __restrict__ A,
                                             const ushort* __restrict__ Bt,
                                             const float* __restrict__ bias,
                                             const float* __restrict__ resid,
                                             const float* __restrict__ lng,
                                             ushort* __restrict__ outb,
                                             float* __restrict__ outf) {
    __shared__ __align__(16) char lds[69632];
    int t = threadIdx.x;
    int l = t & 63, w = t >> 6;
    int lr = l & 15, g = l >> 4;
    int row0 = blockIdx.x * 16;
    f32x4 acc[4] = {};

    const ushort* srcA = A + (size_t)(row0 + (t >> 3)) * 256 + (((t & 7) ^ ((t >> 3) & 7)) << 3);
    const ushort* srcB[8];
#pragma unroll
    for (int q = 0; q < 8; ++q) {
        int cl = q * 32 + (t >> 3);
        srcB[q] = Bt + (size_t)cl * 256 + (((t & 7) ^ (cl & 7)) << 3);
    }
    auto STAGE = [&](int buf) {
        if (t < 128) GLOAD_LDS16(srcA, lds + buf * 2048 + t * 16);
#pragma unroll
        for (int q = 0; q < 8; ++q)
            GLOAD_LDS16(srcB[q], lds + 4096 + buf * 32768 + q * 4096 + t * 16);
        srcA += 64;
#pragma unroll
        for (int q = 0; q < 8; ++q) srcB[q] += 64;
    };

    int sw_a = (lr & 7) << 4;
    int aoff = lr * 128;

    STAGE(0);
#pragma unroll
    for (int c = 0; c < 4; ++c) {
        __syncthreads();
        if (c + 1 < 4) STAGE((c + 1) & 1);
        const char* As = lds + (c & 1) * 2048;
        const char* Ws = lds + 4096 + (c & 1) * 32768;

        short8 a0 = *(const short8*)(As + aoff + ((g * 16) ^ sw_a));
        short8 a1 = *(const short8*)(As + aoff + ((64 + g * 16) ^ sw_a));
#pragma unroll
        for (int n = 0; n < 4; ++n) {
            int cc = w * 64 + n * 16 + lr;
            const char* cb = Ws + cc * 128;
            int sw = (cc & 7) << 4;
            short8 b0 = *(const short8*)(cb + ((g * 16) ^ sw));
            short8 b1 = *(const short8*)(cb + ((64 + g * 16) ^ sw));
            acc[n] = MFMA16(a0, b0, acc[n]);
            acc[n] = MFMA16(a1, b1, acc[n]);
        }
    }
    __syncthreads();

    if constexpr (MODE == 3) {
        ushort(*Ts)[24] = (ushort(*)[24])lds;
#pragma unroll
        for (int n = 0; n < 4; ++n) {
            int c = w * 64 + n * 16 + lr;
            float bi = bias[c];
#pragma unroll
            for (int r = 0; r < 4; ++r)
                Ts[c][g * 4 + r] = f2bf(acc[n][r] + bi);
        }
        __syncthreads();
        {
            int c = t;
            int b = row0 >> 11;
            int n0 = row0 & 2047;
            ushort* dst = outb + ((size_t)(b * 256 + c)) * 2048 + n0;
            *(uint4*)dst = *(uint4*)&Ts[c][0];
            *(uint4*)(dst + 8) = *(uint4*)&Ts[c][8];
        }
    } else {  // MODE 4
        const float* W2 = resid;    // [256][3]
        const float* b2 = lng;      // [3]
        ushort(*Ts)[264] = (ushort(*)[264])lds;
#pragma unroll
        for (int n = 0; n < 4; ++n) {
            int c = w * 64 + n * 16 + lr;
            float bi = bias[c];
#pragma unroll
            for (int r = 0; r < 4; ++r)
                Ts[g * 4 + r][c] = f2bf(fmaxf(acc[n][r] + bi, 0.f));
        }
        __syncthreads();
        int row = t >> 4, sg = t & 15;
        float p0 = 0.f, p1 = 0.f, p2 = 0.f;
#pragma unroll
        for (int e = 0; e < 16; ++e) {
            float x = bf2f(Ts[row][sg * 16 + e]);
            const float* wr = &W2[(sg * 16 + e) * 3];
            p0 += x * wr[0];
            p1 += x * wr[1];
            p2 += x * wr[2];
        }
#pragma unroll
        for (int off = 1; off < 16; off <<= 1) {
            p0 += __shfl_xor(p0, off, 64);
            p1 += __shfl_xor(p1, off, 64);
            p2 += __shfl_xor(p2, off, 64);
        }
        if (sg == 0) {
            int gr = row0 + row;
            outf[gr * 3 + 0] = p0 + b2[0];
            outf[gr * 3 + 1] = p1 + b2[1];
            outf[gr * 3 + 2] = p2 + b2[2];
        }
    }
}

// ---------------------------------------------------------------------------
// gemm_layer (R10): attn-proj -> LN1 -> FFN1 -> ReLU -> FFN2 -> LN2 -> V(l+1).
// ---------------------------------------------------------------------------
__global__ __launch_bounds__(256) void gemm_layer(
        const ushort* __restrict__ attb,
        const ushort* __restrict__ Wat, const float* __restrict__ pb,
        float* __restrict__ feats,
        const float* __restrict__ ln1g, const float* __restrict__ ln1b,
        const ushort* __restrict__ W1t, const float* __restrict__ b1,
        const ushort* __restrict__ W2t, const float* __restrict__ b2,
        const float* __restrict__ ln2g, const float* __restrict__ ln2b,
        ushort* __restrict__ featsb,
        const ushort* __restrict__ WvN, const float* __restrict__ vbN,
        ushort* __restrict__ Vt) {
    __shared__ __align__(16) char lds[61440];
    char* Aa = lds;             // 4KB (2 bufs); red1/red2 overlay after P0
    char* Asp = lds + 4096;     // 8KB: x1 bf16, later x2 bf16
    char* Wsp = lds + 12288;    // 32KB
    char* hidp = lds + 45056;   // 16KB; Ts overlays in P3

    int t = threadIdx.x;
    int l = t & 63, w = t >> 6;
    int lr = l & 15, g = l >> 4;
    int row0 = blockIdx.x * 16;
    int sw_a = (lr & 7) << 4;
    int trow = t >> 3, slot = t & 7;

    uint4 wr0, wr1, wr2, wr3, wr4, wr5, wr6, wr7;
    auto WLOADG = [&](const ushort* Wb, int stride, int colbase, int c) {
        const ushort* base = Wb + c * 64;
#pragma unroll
        for (int q = 0; q < 8; ++q) {
            int cl = colbase + q * 32 + trow;
            uint4 v = *(const uint4*)(base + (size_t)cl * stride + ((slot ^ (cl & 7)) << 3));
            if (q == 0) wr0 = v; else if (q == 1) wr1 = v; else if (q == 2) wr2 = v;
            else if (q == 3) wr3 = v; else if (q == 4) wr4 = v; else if (q == 5) wr5 = v;
            else if (q == 6) wr6 = v; else wr7 = v;
        }
    };
    auto WSTORE = [&]() {
        *(uint4*)(Wsp + 0 * 4096 + t * 16) = wr0;
        *(uint4*)(Wsp + 1 * 4096 + t * 16) = wr1;
        *(uint4*)(Wsp + 2 * 4096 + t * 16) = wr2;
        *(uint4*)(Wsp + 3 * 4096 + t * 16) = wr3;
        *(uint4*)(Wsp + 4 * 4096 + t * 16) = wr4;
        *(uint4*)(Wsp + 5 * 4096 + t * 16) = wr5;
        *(uint4*)(Wsp + 6 * 4096 + t * 16) = wr6;
        *(uint4*)(Wsp + 7 * 4096 + t * 16) = wr7;
    };

    // ---- P0: attn-proj (KD=256), A = attb staged, W = Wat reg-dbuf ----
    const ushort* srcA = attb + (size_t)(row0 + trow) * 256 + ((slot ^ (trow & 7)) << 3);
    auto STAGEA = [&](int buf, int c) {
        if (t < 128) GLOAD_LDS16(srcA + c * 64, Aa + buf * 2048 + t * 16);
    };

    f32x4 acc[4] = {};
    STAGEA(0, 0);
    WLOADG(Wat, 256, 0, 0);
#pragma unroll
    for (int c = 0; c < 4; ++c) {
        __syncthreads();            // Aa[c&1] drained; Wsp free
        WSTORE();
        __syncthreads();            // Wsp visible
        if (c < 3) { WLOADG(Wat, 256, 0, c + 1); STAGEA((c + 1) & 1, c + 1); }
        else WLOADG(W1t, 256, 0, 0);    // prefetch P1 first chunk

        const char* As = Aa + (c & 1) * 2048;
        short8 a0 = *(const short8*)(As + lr * 128 + ((g * 16) ^ sw_a));
        short8 a1 = *(const short8*)(As + lr * 128 + ((64 + g * 16) ^ sw_a));
#pragma unroll
        for (int n = 0; n < 4; ++n) {
            int cc = w * 64 + n * 16 + lr;
            const char* cb = Wsp + cc * 128;
            int sw = (cc & 7) << 4;
            short8 b0 = *(const short8*)(cb + ((g * 16) ^ sw));
            short8 b1 = *(const short8*)(cb + ((64 + g * 16) ^ sw));
            acc[n] = MFMA16(a0, b0, acc[n]);
            acc[n] = MFMA16(a1, b1, acc[n]);
        }
    }
    __syncthreads();

    // ---- LN1 (x1 kept in regs; bf16 to Asp) ----
    float* red1 = (float*)lds;
    float* red2 = (float*)(lds + 512);
    float x1v[4][4];
    {
        float s1[4] = {0.f, 0.f, 0.f, 0.f}, s2[4] = {0.f, 0.f, 0.f, 0.f};
#pragma unroll
        for (int n = 0; n < 4; ++n) {
            int c = w * 64 + n * 16 + lr;
            float bi = pb[c];
#pragma unroll
            for (int r = 0; r < 4; ++r) {
                int row = row0 + g * 4 + r;
                float v = acc[n][r] + bi + feats[(size_t)row * 256 + c];
                x1v[n][r] = v;
                s1[r] += v;
                s2[r] += v * v;
            }
        }
#pragma unroll
        for (int off = 1; off < 16; off <<= 1) {
#pragma unroll
            for (int r = 0; r < 4; ++r) {
                s1[r] += __shfl_xor(s1[r], off, 64);
                s2[r] += __shfl_xor(s2[r], off, 64);
            }
        }
        if (lr == 0) {
#pragma unroll
            for (int r = 0; r < 4; ++r) {
                red1[(g * 4 + r) * 4 + w] = s1[r];
                red2[(g * 4 + r) * 4 + w] = s2[r];
            }
        }
        __syncthreads();
#pragma unroll
        for (int n = 0; n < 4; ++n) {
            int c = w * 64 + n * 16 + lr;
            float gg = ln1g[c], bb = ln1b[c];
#pragma unroll
            for (int r = 0; r < 4; ++r) {
                int rr = g * 4 + r;
                float m1 = red1[rr * 4] + red1[rr * 4 + 1] + red1[rr * 4 + 2] + red1[rr * 4 + 3];
                float m2 = red2[rr * 4] + red2[rr * 4 + 1] + red2[rr * 4 + 2] + red2[rr * 4 + 3];
                float mu = m1 * (1.f / 256.f);
                float var = m2 * (1.f / 256.f) - mu * mu;
                float rstd = rsqrtf(var + 1e-5f);
                float o = (x1v[n][r] - mu) * rstd * gg + bb;
                x1v[n][r] = o;                       // x1 (resid for LN2)
                *(ushort*)(Asp + rr * 512 + ((2 * c) ^ ((rr & 7) << 4))) = f2bf(o);
            }
        }
    }

    // ---- P1: FFN1 (KD=256, COLS=512), A = Asp, relu -> hid LDS ----
#pragma unroll
    for (int ch = 0; ch < 2; ++ch) {
        f32x4 acc1[4] = {};
#pragma unroll
        for (int c = 0; c < 4; ++c) {
            __syncthreads();
            WSTORE();
            __syncthreads();
            if (c < 3) WLOADG(W1t, 256, ch * 256, c + 1);
            else if (ch == 0) WLOADG(W1t, 256, 256, 0);
            else WLOADG(W2t, 512, 0, 0);

            short8 a0 = *(const short8*)(Asp + lr * 512 + ((c * 128 + g * 16) ^ sw_a));
            short8 a1 = *(const short8*)(Asp + lr * 512 + ((c * 128 + 64 + g * 16) ^ sw_a));
#pragma unroll
            for (int n = 0; n < 4; ++n) {
                int cc = w * 64 + n * 16 + lr;
                const char* cb = Wsp + cc * 128;
                int sw = (cc & 7) << 4;
                short8 b0 = *(const short8*)(cb + ((g * 16) ^ sw));
                short8 b1 = *(const short8*)(cb + ((64 + g * 16) ^ sw));
                acc1[n] = MFMA16(a0, b0, acc1[n]);
                acc1[n] = MFMA16(a1, b1, acc1[n]);
            }
        }
#pragma unroll
        for (int n = 0; n < 4; ++n) {
            int c = w * 64 + n * 16 + lr;
            float bi = b1[ch * 256 + c];
#pragma unroll
            for (int r = 0; r < 4; ++r) {
                int rw = g * 4 + r;
                float v = fmaxf(acc1[n][r] + bi, 0.f);
                int byte = rw * 1024 + (((ch * 256 + c) * 2) ^ ((rw & 7) << 4));
                *(ushort*)(hidp + byte) = f2bf(v);
            }
        }
    }

    // ---- P2: FFN2 (KD=512), A = hid LDS ----
    f32x4 acc2[4] = {};
#pragma unroll
    for (int c = 0; c < 8; ++c) {
        __syncthreads();
        WSTORE();
        __syncthreads();
        if (c < 7) WLOADG(W2t, 512, 0, c + 1);
        else if (WvN) WLOADG(WvN, 256, 0, 0);

        short8 a0 = *(const short8*)(hidp + lr * 1024 + ((c * 128 + g * 16) ^ sw_a));
        short8 a1 = *(const short8*)(hidp + lr * 1024 + ((c * 128 + 64 + g * 16) ^ sw_a));
#pragma unroll
        for (int n = 0; n < 4; ++n) {
            int cc = w * 64 + n * 16 + lr;
            const char* cb = Wsp + cc * 128;
            int sw = (cc & 7) << 4;
            short8 b0 = *(const short8*)(cb + ((g * 16) ^ sw));
            short8 b1 = *(const short8*)(cb + ((64 + g * 16) ^ sw));
            acc2[n] = MFMA16(a0, b0, acc2[n]);
            acc2[n] = MFMA16(a1, b1, acc2[n]);
        }
    }
    __syncthreads();

    // ---- LN2 (resid = x1 regs) -> feats fp32+bf16 global; x2 bf16 -> Asp ----
#pragma unroll
    for (int n = 0; n < 4; ++n) {
        int c = w * 64 + n * 16 + lr;
        float bi = b2[c];
#pragma unroll
        for (int r = 0; r < 4; ++r) {
            float v = acc2[n][r] + bi + x1v[n][r];
            acc2[n][r] = v;
        }
    }
    {
        float s1[4] = {0.f, 0.f, 0.f, 0.f}, s2[4] = {0.f, 0.f, 0.f, 0.f};
#pragma unroll
        for (int n = 0; n < 4; ++n)
#pragma unroll
            for (int r = 0; r < 4; ++r) {
                s1[r] += acc2[n][r];
                s2[r] += acc2[n][r] * acc2[n][r];
            }
#pragma unroll
        for (int off = 1; off < 16; off <<= 1) {
#pragma unroll
            for (int r = 0; r < 4; ++r) {
                s1[r] += __shfl_xor(s1[r], off, 64);
                s2[r] += __shfl_xor(s2[r], off, 64);
            }
        }
        if (lr == 0) {
#pragma unroll
            for (int r = 0; r < 4; ++r) {
                red1[(g * 4 + r) * 4 + w] = s1[r];
                red2[(g * 4 + r) * 4 + w] = s2[r];
            }
        }
        __syncthreads();
#pragma unroll
        for (int n = 0; n < 4; ++n) {
            int c = w * 64 + n * 16 + lr;
            float gg = ln2g[c], bb = ln2b[c];
#pragma unroll
            for (int r = 0; r < 4; ++r) {
                int rr = g * 4 + r;
                float m1 = red1[rr * 4] + red1[rr * 4 + 1] + red1[rr * 4 + 2] + red1[rr * 4 + 3];
                float m2 = red2[rr * 4] + red2[rr * 4 + 1] + red2[rr * 4 + 2] + red2[rr * 4 + 3];
                float mu = m1 * (1.f / 256.f);
                float var = m2 * (1.f / 256.f) - mu * mu;
                float rstd = rsqrtf(var + 1e-5f);
                int row = row0 + rr;
                float o = (acc2[n][r] - mu) * rstd * gg + bb;
                feats[(size_t)row * 256 + c] = o;
                ushort ob = f2bf(o);
                featsb[(size_t)row * 256 + c] = ob;
                *(ushort*)(Asp + rr * 512 + ((2 * c) ^ ((rr & 7) << 4))) = ob;
            }
        }
    }

    // ---- P3: V(l+1) = x2 @ WvN (KD=256), transposed bf16 -> Vt ----
    if (WvN) {
        f32x4 acc3[4] = {};
#pragma unroll
        for (int c = 0; c < 4; ++c) {
            __syncthreads();
            WSTORE();
            __syncthreads();
            if (c < 3) WLOADG(WvN, 256, 0, c + 1);

            short8 a0 = *(const short8*)(Asp + lr * 512 + ((c * 128 + g * 16) ^ sw_a));
            short8 a1 = *(const short8*)(Asp + lr * 512 + ((c * 128 + 64 + g * 16) ^ sw_a));
#pragma unroll
            for (int n = 0; n < 4; ++n) {
                int cc = w * 64 + n * 16 + lr;
                const char* cb = Wsp + cc * 128;
                int sw = (cc & 7) << 4;
                short8 b0 = *(const short8*)(cb + ((g * 16) ^ sw));
                short8 b1 = *(const short8*)(cb + ((64 + g * 16) ^ sw));
                acc3[n] = MFMA16(a0, b0, acc3[n]);
                acc3[n] = MFMA16(a1, b1, acc3[n]);
            }
        }
        __syncthreads();
        ushort(*Ts)[24] = (ushort(*)[24])hidp;   // 12KB <= 16KB
#pragma unroll
        for (int n = 0; n < 4; ++n) {
            int c = w * 64 + n * 16 + lr;
            float bi = vbN[c];
#pragma unroll
            for (int r = 0; r < 4; ++r)
                Ts[c][g * 4 + r] = f2bf(acc3[n][r] + bi);
        }
        __syncthreads();
        {
            int c = t;
            int b = row0 >> 11;
            int n0 = row0 & 2047;
            ushort* dst = Vt + ((size_t)(b * 256 + c)) * 2048 + n0;
            *(uint4*)dst = *(uint4*)&Ts[c][0];
            *(uint4*)(dst + 8) = *(uint4*)&Ts[c][8];
        }
    }
}

// ---------------------------------------------------------------------------
extern "C" void kernel_launch(void* const* d_in, const int* in_sizes, int n_in,
                              void* d_out, int out_size, void* d_ws, size_t ws_size,
                              hipStream_t stream) {
    const float* lat    = (const float*)d_in[0];
    const float* xc     = (const float*)d_in[1];
    const float* emb    = (const float*)d_in[2];
    const float* in_W   = (const float*)d_in[3];
    const float* in_b   = (const float*)d_in[4];
    const float* val_W  = (const float*)d_in[5];
    const float* val_b  = (const float*)d_in[6];
    const float* attn_W = (const float*)d_in[7];
    const float* attn_b = (const float*)d_in[8];
    const float* ln1_g  = (const float*)d_in[9];
    const float* ln1_b  = (const float*)d_in[10];
    const float* ln2_g  = (const float*)d_in[11];
    const float* ln2_b  = (const float*)d_in[12];
    const float* ffn_W1 = (const float*)d_in[13];
    const float* ffn_b1 = (const float*)d_in[14];
    const float* ffn_W2 = (const float*)d_in[15];
    const float* ffn_b2 = (const float*)d_in[16];
    const float* out_W1 = (const float*)d_in[17];
    const float* out_b1 = (const float*)d_in[18];
    const float* out_W2 = (const float*)d_in[19];
    const float* out_b2 = (const float*)d_in[20];

    char* W = (char*)d_ws;
    float*  feats  = (float*)W;                                // 8 MB
    ushort* featsb = (ushort*)(W + (8u << 20));                // 4 MB
    ushort* attb   = (ushort*)(W + (12u << 20));               // 4 MB
    ushort* Vt     = (ushort*)(W + (16u << 20));               // 4 MB
    ushort* wp     = (ushort*)(W + (20u << 20));               // 3.2 MB
    uchar*  E8     = (uchar*)(W + (24u << 20));                // 64 MiB fp8
    ushort* Wvt  = wp;
    ushort* Wat  = wp + 262144;
    ushort* W1t  = wp + 524288;
    ushort* W2t  = wp + 1048576;
    ushort* Wo1t = wp + 1572864;

    pack_weights<<<6400, 256, 0, stream>>>(val_W, attn_W, ffn_W1, ffn_W2, out_W1, wp);
    input_mlp<<<R_ / 8, 256, 0, stream>>>(xc, emb, lat, in_W, in_b, feats, featsb);
    ebuild<<<dim3(4, 32, B_), 256, 0, stream>>>(xc, E8);

    gemmM<3><<<R_ / 16, 256, 0, stream>>>(
        featsb, Wvt, val_b, nullptr, nullptr, Vt, nullptr);

    for (int l = 0; l < LAYERS_; ++l) {
        pv_gemm<<<512, 256, 0, stream>>>(E8, Vt, attb);
        const ushort* WvN = (l + 1 < LAYERS_) ? (Wvt + (l + 1) * 65536) : nullptr;
        const float* vbN = val_b + ((l + 1 < LAYERS_) ? (l + 1) * 256 : 0);
        gemm_layer<<<R_ / 16, 256, 0, stream>>>(
            attb, Wat + l * 65536, attn_b + l * 256,
            feats, ln1_g + l * 256, ln1_b + l * 256,
            W1t + l * 131072, ffn_b1 + l * 512,
            W2t + l * 131072, ffn_b2 + l * 256,
            ln2_g + l * 256, ln2_b + l * 256,
            featsb, WvN, vbN, Vt);
    }

    gemmM<4><<<R_ / 16, 256, 0, stream>>>(
        featsb, Wo1t, out_b1, out_W2, out_b2, nullptr, (float*)d_out);
}

// Round 15
// 256.743 us; speedup vs baseline: 1.4239x; 1.0476x over previous
//
#include <hip/hip_runtime.h>

#define B_ 4
#define N_ 2048
#define R_ (B_ * N_)      // 8192 rows
#define HID_ 256
#define EMB_ 64
#define IN_DIM_ 70
#define H_ 4
#define HEAD_ 64
#define FFN_ 512
#define LAYERS_ 4

typedef __attribute__((ext_vector_type(8))) short short8;
typedef __attribute__((ext_vector_type(4))) float f32x4;
typedef unsigned short ushort;

static __device__ __forceinline__ ushort f2bf(float f) {
    unsigned u = __builtin_bit_cast(unsigned, f);
    u += 0x7fffu + ((u >> 16) & 1u);   // RNE
    return (ushort)(u >> 16);
}
static __device__ __forceinline__ float bf2f(ushort u) {
    unsigned x = ((unsigned)u) << 16;
    return __builtin_bit_cast(float, x);
}

#define GLOAD_LDS16(g, l)                                              \
    __builtin_amdgcn_global_load_lds(                                  \
        (const __attribute__((address_space(1))) void*)(g),            \
        (__attribute__((address_space(3))) void*)(l), 16, 0, 0)

#define MFMA16(a, b, c) __builtin_amdgcn_mfma_f32_16x16x32_bf16(a, b, c, 0, 0, 0)

// ---------------------------------------------------------------------------
// Pack all weights to bf16, transposed [c][k] layout.
// ---------------------------------------------------------------------------
__global__ __launch_bounds__(256) void pack_weights(const float* __restrict__ valW,
                                                    const float* __restrict__ attnW,
                                                    const float* __restrict__ ffnW1,
                                                    const float* __restrict__ ffnW2,
                                                    const float* __restrict__ outW1,
                                                    ushort* __restrict__ wp) {
    int idx = blockIdx.x * 256 + threadIdx.x;
    float v;
    if (idx < 262144) {
        int l = idx >> 16, c = (idx >> 8) & 255, k = idx & 255;
        v = valW[((l * 4 + (c >> 6)) * 256 + k) * 64 + (c & 63)];
    } else if (idx < 524288) {
        int i2 = idx - 262144;
        int l = i2 >> 16, c = (i2 >> 8) & 255, k = i2 & 255;
        v = attnW[l * 65536 + k * 256 + c];
    } else if (idx < 1048576) {
        int i2 = idx - 524288;
        int l = i2 >> 17, c = (i2 >> 8) & 511, k = i2 & 255;
        v = ffnW1[l * 131072 + k * 512 + c];
    } else if (idx < 1572864) {
        int i2 = idx - 1048576;
        int l = i2 >> 17, c = (i2 >> 9) & 255, k = i2 & 511;
        v = ffnW2[l * 131072 + k * 256 + c];
    } else {
        int i2 = idx - 1572864;
        int c = i2 >> 8, k = i2 & 255;
        v = outW1[k * 256 + c];
    }
    wp[idx] = f2bf(v);
}

// ---------------------------------------------------------------------------
// Input MLP
// ---------------------------------------------------------------------------
__global__ __launch_bounds__(256) void input_mlp(const float* __restrict__ xc,
                                                 const float* __restrict__ emb,
                                                 const float* __restrict__ lat,
                                                 const float* __restrict__ W,
                                                 const float* __restrict__ b,
                                                 float* __restrict__ feats,
                                                 ushort* __restrict__ featsb) {
    __shared__ float xr[8][IN_DIM_ + 2];
    int t = threadIdx.x;
    int row0 = blockIdx.x * 8;
    for (int idx = t; idx < 8 * IN_DIM_; idx += 256) {
        int r = idx / IN_DIM_, f = idx % IN_DIM_;
        int rr = row0 + r;
        float v;
        if (f < 3)       v = xc[rr * 3 + f];
        else if (f < 67) v = emb[rr * EMB_ + (f - 3)];
        else             v = lat[rr * 3 + (f - 67)];
        xr[r][f] = v;
    }
    __syncthreads();
    float acc[8] = {0.f, 0.f, 0.f, 0.f, 0.f, 0.f, 0.f, 0.f};
    for (int f = 0; f < IN_DIM_; ++f) {
        float w = W[f * HID_ + t];
#pragma unroll
        for (int r = 0; r < 8; ++r) acc[r] += xr[r][f] * w;
    }
    float bb = b[t];
#pragma unroll
    for (int r = 0; r < 8; ++r) {
        float v = fmaxf(acc[r] + bb, 0.f);
        feats[(row0 + r) * HID_ + t] = v;
        featsb[(row0 + r) * HID_ + t] = f2bf(v);
    }
}

// ---------------------------------------------------------------------------
// ebuild: E[h][b][i][j] bf16, built once (R10 version, uint4 stores).
// ---------------------------------------------------------------------------
__global__ __launch_bounds__(256) void ebuild(const float* __restrict__ xc,
                                              ushort* __restrict__ E) {
    __shared__ float4 civ[64];
    __shared__ float4 cjv[512];
    int t = threadIdx.x;
    int jb = blockIdx.x;
    int ibl = blockIdx.y;
    int b = blockIdx.z;
    const float* xb = xc + (size_t)b * N_ * 3;
    if (t < 64) {
        const float* p = &xb[(ibl * 64 + t) * 3];
        float x = p[0], y = p[1], z = p[2];
        civ[t] = make_float4(x, y, z, x * x + y * y + z * z);
    }
#pragma unroll
    for (int s = 0; s < 2; ++s) {
        int j = s * 256 + t;
        const float* p = &xb[(jb * 512 + j) * 3];
        float x = p[0], y = p[1], z = p[2];
        cjv[j] = make_float4(x, y, z, x * x + y * y + z * z);
    }
    __syncthreads();
    int lane = t & 63, ig = t >> 6;
    float4 cj[8];
#pragma unroll
    for (int e = 0; e < 8; ++e) cj[e] = cjv[lane * 8 + e];
    const float ch0 = -4.f * 1.44269504088896f;
    ushort* Ebase = E + ((size_t)b * 2048 + ibl * 64) * 2048 + (size_t)jb * 512 + lane * 8;

    for (int r = 0; r < 16; ++r) {
        int i = ig * 16 + r;
        float4 ci = civ[i];
        float d[8];
#pragma unroll
        for (int e = 0; e < 8; ++e)
            d[e] = (ci.w + cj[e].w) -
                   2.f * (ci.x * cj[e].x + ci.y * cj[e].y + ci.z * cj[e].z);
        float ch = ch0;
#pragma unroll
        for (int h = 0; h < 4; ++h) {
            float ex[8];
#pragma unroll
            for (int e = 0; e < 8; ++e) ex[e] = exp2f(d[e] * ch);
            union { unsigned u[4]; uint4 v; } pk;
#pragma unroll
            for (int q = 0; q < 4; ++q)
                asm("v_cvt_pk_bf16_f32 %0, %1, %2"
                    : "=v"(pk.u[q]) : "v"(ex[2 * q]), "v"(ex[2 * q + 1]));
            *(uint4*)(Ebase + (size_t)h * 4 * 2048 * 2048 + (size_t)i * 2048) = pk.v;
            ch *= 0.25f;
        }
    }
}

// ---------------------------------------------------------------------------
// pv_gemm (R10 version): E+V both LDS-staged via global_load_lds, dbuf,
// 1 barrier/chunk. 64 i x 64 cols per block, grid 512 XCD-decoded.
// ---------------------------------------------------------------------------
__global__ __launch_bounds__(256, 2) void pv_gemm(const ushort* __restrict__ E,
                                                  const ushort* __restrict__ Vt,
                                                  ushort* __restrict__ attb) {
    __shared__ __align__(16) char lds[32768];   // [2] x (A 8KB + B 8KB)
    int t = threadIdx.x;
    int l = t & 63, w = t >> 6;
    int lr = l & 15, g = l >> 4;

    int f = blockIdx.x;                 // 512 blocks
    int xcd = f & 7, s = f >> 3;
    int combo = xcd * 2 + (s >> 5);     // 0..15
    int ib = s & 31;
    int b = combo & 3, h = combo >> 2;
    int i_base = ib * 64;
    int hc = h * 64;

    const ushort* Eb = E + (size_t)(h * 4 + b) * 2048 * 2048;
    int slot = t & 7, trow = t >> 3;

    const ushort* srcA[2];
    const ushort* srcB[2];
#pragma unroll
    for (int q = 0; q < 2; ++q) {
        int arow = q * 32 + trow;
        srcA[q] = Eb + (size_t)(i_base + arow) * 2048 + ((slot ^ (arow & 7)) << 3);
        int cl = q * 32 + trow;
        srcB[q] = Vt + (size_t)(b * 256 + hc + cl) * 2048 + ((slot ^ (cl & 7)) << 3);
    }
    auto STAGE = [&](int buf) {
#pragma unroll
        for (int q = 0; q < 2; ++q)
            GLOAD_LDS16(srcA[q], lds + buf * 16384 + q * 4096 + t * 16);
#pragma unroll
        for (int q = 0; q < 2; ++q)
            GLOAD_LDS16(srcB[q], lds + buf * 16384 + 8192 + q * 4096 + t * 16);
#pragma unroll
        for (int q = 0; q < 2; ++q) { srcA[q] += 64; srcB[q] += 64; }
    };

    f32x4 acc[4] = {};
    f32x4 accd = {};
    short8 ones = {0x3F80, 0x3F80, 0x3F80, 0x3F80, 0x3F80, 0x3F80, 0x3F80, 0x3F80};

    int arow = w * 16 + lr;
    int aoff = arow * 128;
    int sw_a = (arow & 7) << 4;

    STAGE(0);
    for (int c = 0; c < 32; ++c) {
        __syncthreads();
        if (c + 1 < 32) STAGE((c + 1) & 1);
        const char* As = lds + (c & 1) * 16384;
        const char* Bs = As + 8192;

        short8 a0 = *(const short8*)(As + aoff + ((g * 16) ^ sw_a));
        short8 a1 = *(const short8*)(As + aoff + ((64 + g * 16) ^ sw_a));
        accd = MFMA16(a0, ones, accd);
        accd = MFMA16(a1, ones, accd);
#pragma unroll
        for (int n = 0; n < 4; ++n) {
            int cc = n * 16 + lr;
            const char* cb = Bs + cc * 128;
            int sw = (cc & 7) << 4;
            short8 b0 = *(const short8*)(cb + ((g * 16) ^ sw));
            short8 b1 = *(const short8*)(cb + ((64 + g * 16) ^ sw));
            acc[n] = MFMA16(a0, b0, acc[n]);
            acc[n] = MFMA16(a1, b1, acc[n]);
        }
    }

#pragma unroll
    for (int r = 0; r < 4; ++r) {
        float invd = 1.f / (accd[r] + 1e-8f);
        int row = i_base + w * 16 + g * 4 + r;
        size_t rb = ((size_t)b * N_ + row) * 256 + hc + lr;
#pragma unroll
        for (int n = 0; n < 4; ++n)
            attb[rb + n * 16] = f2bf(acc[n][r] * invd);
    }
}

// ---------------------------------------------------------------------------
// gemmM (R10): LDS-dbuf staged A+B, KD=256. MODE 3 / MODE 4.
// ---------------------------------------------------------------------------
template <int MODE>
__global__ __launch_bounds__(256) void gemmM(const ushort* __restrict__ A,
                                             const ushort* __restrict__ Bt,
                                             const float* __restrict__ bias,
                                             const float* __restrict__ resid,
                                             const float* __restrict__ lng,
                                             ushort* __restrict__ outb,
                                             float* __restrict__ outf) {
    __shared__ __align__(16) char lds[69632];
    int t = threadIdx.x;
    int l = t & 63, w = t >> 6;
    int lr = l & 15, g = l >> 4;
    int row0 = blockIdx.x * 16;
    f32x4 acc[4] = {};

    const ushort* srcA = A + (size_t)(row0 + (t >> 3)) * 256 + (((t & 7) ^ ((t >> 3) & 7)) << 3);
    const ushort* srcB[8];
#pragma unroll
    for (int q = 0; q < 8; ++q) {
        int cl = q * 32 + (t >> 3);
        srcB[q] = Bt + (size_t)cl * 256 + (((t & 7) ^ (cl & 7)) << 3);
    }
    auto STAGE = [&](int buf) {
        if (t < 128) GLOAD_LDS16(srcA, lds + buf * 2048 + t * 16);
#pragma unroll
        for (int q = 0; q < 8; ++q)
            GLOAD_LDS16(srcB[q], lds + 4096 + buf * 32768 + q * 4096 + t * 16);
        srcA += 64;
#pragma unroll
        for (int q = 0; q < 8; ++q) srcB[q] += 64;
    };

    int sw_a = (lr & 7) << 4;
    int aoff = lr * 128;

    STAGE(0);
#pragma unroll
    for (int c = 0; c < 4; ++c) {
        __syncthreads();
        if (c + 1 < 4) STAGE((c + 1) & 1);
        const char* As = lds + (c & 1) * 2048;
        const char* Ws = lds + 4096 + (c & 1) * 32768;

        short8 a0 = *(const short8*)(As + aoff + ((g * 16) ^ sw_a));
        short8 a1 = *(const short8*)(As + aoff + ((64 + g * 16) ^ sw_a));
#pragma unroll
        for (int n = 0; n < 4; ++n) {
            int cc = w * 64 + n * 16 + lr;
            const char* cb = Ws + cc * 128;
            int sw = (cc & 7) << 4;
            short8 b0 = *(const short8*)(cb + ((g * 16) ^ sw));
            short8 b1 = *(const short8*)(cb + ((64 + g * 16) ^ sw));
            acc[n] = MFMA16(a0, b0, acc[n]);
            acc[n] = MFMA16(a1, b1, acc[n]);
        }
    }
    __syncthreads();

    if constexpr (MODE == 3) {
        ushort(*Ts)[24] = (ushort(*)[24])lds;
#pragma unroll
        for (int n = 0; n < 4; ++n) {
            int c = w * 64 + n * 16 + lr;
            float bi = bias[c];
#pragma unroll
            for (int r = 0; r < 4; ++r)
                Ts[c][g * 4 + r] = f2bf(acc[n][r] + bi);
        }
        __syncthreads();
        {
            int c = t;
            int b = row0 >> 11;
            int n0 = row0 & 2047;
            ushort* dst = outb + ((size_t)(b * 256 + c)) * 2048 + n0;
            *(uint4*)dst = *(uint4*)&Ts[c][0];
            *(uint4*)(dst + 8) = *(uint4*)&Ts[c][8];
        }
    } else {  // MODE 4
        const float* W2 = resid;    // [256][3]
        const float* b2 = lng;      // [3]
        ushort(*Ts)[264] = (ushort(*)[264])lds;
#pragma unroll
        for (int n = 0; n < 4; ++n) {
            int c = w * 64 + n * 16 + lr;
            float bi = bias[c];
#pragma unroll
            for (int r = 0; r < 4; ++r)
                Ts[g * 4 + r][c] = f2bf(fmaxf(acc[n][r] + bi, 0.f));
        }
        __syncthreads();
        int row = t >> 4, sg = t & 15;
        float p0 = 0.f, p1 = 0.f, p2 = 0.f;
#pragma unroll
        for (int e = 0; e < 16; ++e) {
            float x = bf2f(Ts[row][sg * 16 + e]);
            const float* wr = &W2[(sg * 16 + e) * 3];
            p0 += x * wr[0];
            p1 += x * wr[1];
            p2 += x * wr[2];
        }
#pragma unroll
        for (int off = 1; off < 16; off <<= 1) {
            p0 += __shfl_xor(p0, off, 64);
            p1 += __shfl_xor(p1, off, 64);
            p2 += __shfl_xor(p2, off, 64);
        }
        if (sg == 0) {
            int gr = row0 + row;
            outf[gr * 3 + 0] = p0 + b2[0];
            outf[gr * 3 + 1] = p1 + b2[1];
            outf[gr * 3 + 2] = p2 + b2[2];
        }
    }
}

// ---------------------------------------------------------------------------
// gemm_layer v4: M-tile 32, 512 threads = 8 waves (wave = colgroup cg x
// row-half mh). Same R10 weight pipeline (reg-dbuf WLOADG under compute,
// WSTORE between barriers), but each Wsp fragment now feeds 2 waves and
// per-layer weight L2 traffic halves (335->167 MB). LDS 89KB, 1 block/CU.
// ---------------------------------------------------------------------------
__global__ __launch_bounds__(512) void gemm_layer(
        const ushort* __restrict__ attb,
        const ushort* __restrict__ Wat, const float* __restrict__ pb,
        float* __restrict__ feats,
        const float* __restrict__ ln1g, const float* __restrict__ ln1b,
        const ushort* __restrict__ W1t, const float* __restrict__ b1,
        const ushort* __restrict__ W2t, const float* __restrict__ b2,
        const float* __restrict__ ln2g, const float* __restrict__ ln2b,
        ushort* __restrict__ featsb,
        const ushort* __restrict__ WvN, const float* __restrict__ vbN,
        ushort* __restrict__ Vt) {
    __shared__ __align__(16) char lds[91136];
    char* Aa = lds;             // 8KB (2x4KB); red1/red2 overlay after P0
    char* Asp = lds + 8192;     // 16KB: x1 bf16, later x2 bf16 (32 rows x 512B)
    char* Wsp = lds + 24576;    // 32KB (256 cols x 128B)
    char* hidp = lds + 57344;   // 32KB (32 rows x 1024B); Ts overlays in P3

    int t = threadIdx.x;
    int l = t & 63, w = t >> 6;     // w 0..7
    int cg = w & 3, mh = w >> 2;    // col-group, row-half
    int lr = l & 15, g = l >> 4;
    int row0 = blockIdx.x * 32;
    int arow = mh * 16 + lr;        // wave's fragment row 0..31
    int sw_a = (lr & 7) << 4;
    int trow = t >> 3, slot = t & 7;  // trow 0..63

    uint4 wr0, wr1, wr2, wr3;
    auto WLOADG = [&](const ushort* Wb, int stride, int colbase, int c) {
        const ushort* base = Wb + c * 64;
#pragma unroll
        for (int q = 0; q < 4; ++q) {
            int cl = colbase + q * 64 + trow;
            uint4 v = *(const uint4*)(base + (size_t)cl * stride + ((slot ^ (cl & 7)) << 3));
            if (q == 0) wr0 = v; else if (q == 1) wr1 = v;
            else if (q == 2) wr2 = v; else wr3 = v;
        }
    };
    auto WSTORE = [&]() {
        *(uint4*)(Wsp + 0 * 8192 + t * 16) = wr0;
        *(uint4*)(Wsp + 1 * 8192 + t * 16) = wr1;
        *(uint4*)(Wsp + 2 * 8192 + t * 16) = wr2;
        *(uint4*)(Wsp + 3 * 8192 + t * 16) = wr3;
    };

    // ---- P0: attn-proj (KD=256), A = attb staged (32 rows), W reg-dbuf ----
    const ushort* srcA = attb + (size_t)(row0 + trow) * 256 + ((slot ^ (trow & 7)) << 3);
    auto STAGEA = [&](int buf, int c) {
        if (t < 256) GLOAD_LDS16(srcA + c * 64, Aa + buf * 4096 + t * 16);
    };

    f32x4 acc0[4] = {};
    STAGEA(0, 0);
    WLOADG(Wat, 256, 0, 0);
#pragma unroll
    for (int c = 0; c < 4; ++c) {
        __syncthreads();            // Aa[c&1]+Wsp loads drained; Wsp free
        WSTORE();
        __syncthreads();            // Wsp visible
        if (c < 3) { WLOADG(Wat, 256, 0, c + 1); STAGEA((c + 1) & 1, c + 1); }
        else WLOADG(W1t, 256, 0, 0);

        const char* As = Aa + (c & 1) * 4096;
        short8 a0 = *(const short8*)(As + arow * 128 + ((g * 16) ^ sw_a));
        short8 a1 = *(const short8*)(As + arow * 128 + ((64 + g * 16) ^ sw_a));
#pragma unroll
        for (int n = 0; n < 4; ++n) {
            int cc = cg * 64 + n * 16 + lr;
            const char* cb = Wsp + cc * 128;
            int sw = (cc & 7) << 4;
            short8 b0 = *(const short8*)(cb + ((g * 16) ^ sw));
            short8 b1 = *(const short8*)(cb + ((64 + g * 16) ^ sw));
            acc0[n] = MFMA16(a0, b0, acc0[n]);
            acc0[n] = MFMA16(a1, b1, acc0[n]);
        }
    }
    __syncthreads();

    // ---- LN1 (x1 in regs; bf16 -> Asp) ----
    float* red1 = (float*)lds;          // [32][4]
    float* red2 = (float*)(lds + 512);
    float x1v[4][4];
    {
        float s1[4] = {0.f, 0.f, 0.f, 0.f}, s2[4] = {0.f, 0.f, 0.f, 0.f};
#pragma unroll
        for (int n = 0; n < 4; ++n) {
            int c = cg * 64 + n * 16 + lr;
            float bi = pb[c];
#pragma unroll
            for (int r = 0; r < 4; ++r) {
                int row = row0 + mh * 16 + g * 4 + r;
                float v = acc0[n][r] + bi + feats[(size_t)row * 256 + c];
                x1v[n][r] = v;
                s1[r] += v;
                s2[r] += v * v;
            }
        }
#pragma unroll
        for (int off = 1; off < 16; off <<= 1) {
#pragma unroll
            for (int r = 0; r < 4; ++r) {
                s1[r] += __shfl_xor(s1[r], off, 64);
                s2[r] += __shfl_xor(s2[r], off, 64);
            }
        }
        if (lr == 0) {
#pragma unroll
            for (int r = 0; r < 4; ++r) {
                red1[(mh * 16 + g * 4 + r) * 4 + cg] = s1[r];
                red2[(mh * 16 + g * 4 + r) * 4 + cg] = s2[r];
            }
        }
        __syncthreads();
#pragma unroll
        for (int n = 0; n < 4; ++n) {
            int c = cg * 64 + n * 16 + lr;
            float gg = ln1g[c], bb = ln1b[c];
#pragma unroll
            for (int r = 0; r < 4; ++r) {
                int rr = mh * 16 + g * 4 + r;
                float m1 = red1[rr * 4] + red1[rr * 4 + 1] + red1[rr * 4 + 2] + red1[rr * 4 + 3];
                float m2 = red2[rr * 4] + red2[rr * 4 + 1] + red2[rr * 4 + 2] + red2[rr * 4 + 3];
                float mu = m1 * (1.f / 256.f);
                float var = m2 * (1.f / 256.f) - mu * mu;
                float rstd = rsqrtf(var + 1e-5f);
                float o = (x1v[n][r] - mu) * rstd * gg + bb;
                x1v[n][r] = o;
                *(ushort*)(Asp + rr * 512 + ((2 * c) ^ ((rr & 7) << 4))) = f2bf(o);
            }
        }
    }

    // ---- P1: FFN1 (KD=256, 512 cols in 2 halves), A = Asp, relu -> hid ----
#pragma unroll
    for (int ch = 0; ch < 2; ++ch) {
        f32x4 acc1[4] = {};
#pragma unroll
        for (int c = 0; c < 4; ++c) {
            __syncthreads();
            WSTORE();
            __syncthreads();
            if (c < 3) WLOADG(W1t, 256, ch * 256, c + 1);
            else if (ch == 0) WLOADG(W1t, 256, 256, 0);
            else WLOADG(W2t, 512, 0, 0);

            short8 a0 = *(const short8*)(Asp + arow * 512 + ((c * 128 + g * 16) ^ sw_a));
            short8 a1 = *(const short8*)(Asp + arow * 512 + ((c * 128 + 64 + g * 16) ^ sw_a));
#pragma unroll
            for (int n = 0; n < 4; ++n) {
                int cc = cg * 64 + n * 16 + lr;
                const char* cb = Wsp + cc * 128;
                int sw = (cc & 7) << 4;
                short8 b0 = *(const short8*)(cb + ((g * 16) ^ sw));
                short8 b1 = *(const short8*)(cb + ((64 + g * 16) ^ sw));
                acc1[n] = MFMA16(a0, b0, acc1[n]);
                acc1[n] = MFMA16(a1, b1, acc1[n]);
            }
        }
#pragma unroll
        for (int n = 0; n < 4; ++n) {
            int cf = ch * 256 + cg * 64 + n * 16 + lr;
            float bi = b1[cf];
#pragma unroll
            for (int r = 0; r < 4; ++r) {
                int rw = mh * 16 + g * 4 + r;
                float v = fmaxf(acc1[n][r] + bi, 0.f);
                *(ushort*)(hidp + rw * 1024 + ((cf * 2) ^ ((rw & 7) << 4))) = f2bf(v);
            }
        }
    }

    // ---- P2: FFN2 (KD=512), A = hid ----
    f32x4 acc2[4] = {};
#pragma unroll
    for (int c = 0; c < 8; ++c) {
        __syncthreads();
        WSTORE();
        __syncthreads();
        if (c < 7) WLOADG(W2t, 512, 0, c + 1);
        else if (WvN) WLOADG(WvN, 256, 0, 0);

        short8 a0 = *(const short8*)(hidp + arow * 1024 + ((c * 128 + g * 16) ^ sw_a));
        short8 a1 = *(const short8*)(hidp + arow * 1024 + ((c * 128 + 64 + g * 16) ^ sw_a));
#pragma unroll
        for (int n = 0; n < 4; ++n) {
            int cc = cg * 64 + n * 16 + lr;
            const char* cb = Wsp + cc * 128;
            int sw = (cc & 7) << 4;
            short8 b0 = *(const short8*)(cb + ((g * 16) ^ sw));
            short8 b1 = *(const short8*)(cb + ((64 + g * 16) ^ sw));
            acc2[n] = MFMA16(a0, b0, acc2[n]);
            acc2[n] = MFMA16(a1, b1, acc2[n]);
        }
    }
    __syncthreads();

    // ---- LN2 (resid = x1 regs) -> feats fp32+bf16; x2 -> Asp ----
#pragma unroll
    for (int n = 0; n < 4; ++n) {
        int c = cg * 64 + n * 16 + lr;
        float bi = b2[c];
#pragma unroll
        for (int r = 0; r < 4; ++r)
            acc2[n][r] = acc2[n][r] + bi + x1v[n][r];
    }
    {
        float* red1b = (float*)lds;
        float* red2b = (float*)(lds + 512);
        float s1[4] = {0.f, 0.f, 0.f, 0.f}, s2[4] = {0.f, 0.f, 0.f, 0.f};
#pragma unroll
        for (int n = 0; n < 4; ++n)
#pragma unroll
            for (int r = 0; r < 4; ++r) {
                s1[r] += acc2[n][r];
                s2[r] += acc2[n][r] * acc2[n][r];
            }
#pragma unroll
        for (int off = 1; off < 16; off <<= 1) {
#pragma unroll
            for (int r = 0; r < 4; ++r) {
                s1[r] += __shfl_xor(s1[r], off, 64);
                s2[r] += __shfl_xor(s2[r], off, 64);
            }
        }
        if (lr == 0) {
#pragma unroll
            for (int r = 0; r < 4; ++r) {
                red1b[(mh * 16 + g * 4 + r) * 4 + cg] = s1[r];
                red2b[(mh * 16 + g * 4 + r) * 4 + cg] = s2[r];
            }
        }
        __syncthreads();
#pragma unroll
        for (int n = 0; n < 4; ++n) {
            int c = cg * 64 + n * 16 + lr;
            float gg = ln2g[c], bb = ln2b[c];
#pragma unroll
            for (int r = 0; r < 4; ++r) {
                int rr = mh * 16 + g * 4 + r;
                float m1 = red1b[rr * 4] + red1b[rr * 4 + 1] + red1b[rr * 4 + 2] + red1b[rr * 4 + 3];
                float m2 = red2b[rr * 4] + red2b[rr * 4 + 1] + red2b[rr * 4 + 2] + red2b[rr * 4 + 3];
                float mu = m1 * (1.f / 256.f);
                float var = m2 * (1.f / 256.f) - mu * mu;
                float rstd = rsqrtf(var + 1e-5f);
                int row = row0 + rr;
                float o = (acc2[n][r] - mu) * rstd * gg + bb;
                feats[(size_t)row * 256 + c] = o;
                ushort ob = f2bf(o);
                featsb[(size_t)row * 256 + c] = ob;
                *(ushort*)(Asp + rr * 512 + ((2 * c) ^ ((rr & 7) << 4))) = ob;
            }
        }
    }
    __syncthreads();

    // ---- P3: V(l+1) = x2 @ WvN (KD=256), transposed bf16 -> Vt ----
    if (WvN) {
        f32x4 acc3[4] = {};
#pragma unroll
        for (int c = 0; c < 4; ++c) {
            __syncthreads();
            WSTORE();
            __syncthreads();
            if (c < 3) WLOADG(WvN, 256, 0, c + 1);

            short8 a0 = *(const short8*)(Asp + arow * 512 + ((c * 128 + g * 16) ^ sw_a));
            short8 a1 = *(const short8*)(Asp + arow * 512 + ((c * 128 + 64 + g * 16) ^ sw_a));
#pragma unroll
            for (int n = 0; n < 4; ++n) {
                int cc = cg * 64 + n * 16 + lr;
                const char* cb = Wsp + cc * 128;
                int sw = (cc & 7) << 4;
                short8 b0 = *(const short8*)(cb + ((g * 16) ^ sw));
                short8 b1 = *(const short8*)(cb + ((64 + g * 16) ^ sw));
                acc3[n] = MFMA16(a0, b0, acc3[n]);
                acc3[n] = MFMA16(a1, b1, acc3[n]);
            }
        }
        __syncthreads();
        ushort(*Ts)[40] = (ushort(*)[40])hidp;   // [256][40] = 20KB <= 32KB
#pragma unroll
        for (int n = 0; n < 4; ++n) {
            int c = cg * 64 + n * 16 + lr;
            float bi = vbN[c];
#pragma unroll
            for (int r = 0; r < 4; ++r)
                Ts[c][mh * 16 + g * 4 + r] = f2bf(acc3[n][r] + bi);
        }
        __syncthreads();
        if (t < 256) {
            int c = t;
            int b = row0 >> 11;
            int n0 = row0 & 2047;
            ushort* dst = Vt + ((size_t)(b * 256 + c)) * 2048 + n0;
            *(uint4*)dst = *(uint4*)&Ts[c][0];
            *(uint4*)(dst + 8) = *(uint4*)&Ts[c][8];
            *(uint4*)(dst + 16) = *(uint4*)&Ts[c][16];
            *(uint4*)(dst + 24) = *(uint4*)&Ts[c][24];
        }
    }
}

// ---------------------------------------------------------------------------
extern "C" void kernel_launch(void* const* d_in, const int* in_sizes, int n_in,
                              void* d_out, int out_size, void* d_ws, size_t ws_size,
                              hipStream_t stream) {
    const float* lat    = (const float*)d_in[0];
    const float* xc     = (const float*)d_in[1];
    const float* emb    = (const float*)d_in[2];
    const float* in_W   = (const float*)d_in[3];
    const float* in_b   = (const float*)d_in[4];
    const float* val_W  = (const float*)d_in[5];
    const float* val_b  = (const float*)d_in[6];
    const float* attn_W = (const float*)d_in[7];
    const float* attn_b = (const float*)d_in[8];
    const float* ln1_g  = (const float*)d_in[9];
    const float* ln1_b  = (const float*)d_in[10];
    const float* ln2_g  = (const float*)d_in[11];
    const float* ln2_b  = (const float*)d_in[12];
    const float* ffn_W1 = (const float*)d_in[13];
    const float* ffn_b1 = (const float*)d_in[14];
    const float* ffn_W2 = (const float*)d_in[15];
    const float* ffn_b2 = (const float*)d_in[16];
    const float* out_W1 = (const float*)d_in[17];
    const float* out_b1 = (const float*)d_in[18];
    const float* out_W2 = (const float*)d_in[19];
    const float* out_b2 = (const float*)d_in[20];

    char* W = (char*)d_ws;
    float*  feats  = (float*)W;                                // 8 MB
    ushort* featsb = (ushort*)(W + (8u << 20));                // 4 MB
    ushort* attb   = (ushort*)(W + (12u << 20));               // 4 MB
    ushort* Vt     = (ushort*)(W + (16u << 20));               // 4 MB
    ushort* wp     = (ushort*)(W + (20u << 20));               // 3.2 MB
    ushort* E      = (ushort*)(W + (24u << 20));               // 128 MiB bf16
    ushort* Wvt  = wp;
    ushort* Wat  = wp + 262144;
    ushort* W1t  = wp + 524288;
    ushort* W2t  = wp + 1048576;
    ushort* Wo1t = wp + 1572864;

    pack_weights<<<6400, 256, 0, stream>>>(val_W, attn_W, ffn_W1, ffn_W2, out_W1, wp);
    input_mlp<<<R_ / 8, 256, 0, stream>>>(xc, emb, lat, in_W, in_b, feats, featsb);
    ebuild<<<dim3(4, 32, B_), 256, 0, stream>>>(xc, E);

    gemmM<3><<<R_ / 16, 256, 0, stream>>>(
        featsb, Wvt, val_b, nullptr, nullptr, Vt, nullptr);

    for (int l = 0; l < LAYERS_; ++l) {
        pv_gemm<<<512, 256, 0, stream>>>(E, Vt, attb);
        const ushort* WvN = (l + 1 < LAYERS_) ? (Wvt + (l + 1) * 65536) : nullptr;
        const float* vbN = val_b + ((l + 1 < LAYERS_) ? (l + 1) * 256 : 0);
        gemm_layer<<<R_ / 32, 512, 0, stream>>>(
            attb, Wat + l * 65536, attn_b + l * 256,
            feats, ln1_g + l * 256, ln1_b + l * 256,
            W1t + l * 131072, ffn_b1 + l * 512,
            W2t + l * 131072, ffn_b2 + l * 256,
            ln2_g + l * 256, ln2_b + l * 256,
            featsb, WvN, vbN, Vt);
    }

    gemmM<4><<<R_ / 16, 256, 0, stream>>>(
        featsb, Wo1t, out_b1, out_W2, out_b2, nullptr, (float*)d_out);
}